// Round 1
// baseline (1798.675 us; speedup 1.0000x reference)
//
#include <hip/hip_runtime.h>

// ---------------------------------------------------------------------------
// MoEPredictor on MI355X (gfx950) — Round 4: 2-phase double-buffered GEMMs.
//
// Pipeline unchanged from R3 except all MFMA GEMMs move to a templated
// 2-phase (stage-ahead, double-buffered LDS, BK=64) kernel:
//   - gate/up:  256x256 tile, 8 waves, 128 KB LDS, 1 block/CU
//   - down + in/out proj: 128x128 tile, 4 waves, 64 KB LDS, 2 blocks/CU
// Expert segments now padded to 256 rows (for the 256-row tiles).
// XCD-aware bijective block swizzle (T1/m204) on all GEMM grids.
// ---------------------------------------------------------------------------

#define NT      8192
#define DMODEL  1024
#define DFF     4096
#define NEXP    8
#define MAXROWS (NT * 2 + NEXP * 256)  // 18432 padded compact rows max
#define RMS_EPS 1.1920928955078125e-07f  // jnp.finfo(float32).eps

typedef __attribute__((ext_vector_type(8))) short bf16x8;   // MFMA A/B frag
typedef __attribute__((ext_vector_type(4))) float f32x4;    // MFMA C/D frag

__device__ __forceinline__ float bf2f(unsigned short u) {
  union { unsigned int i; float f; } c; c.i = ((unsigned int)u) << 16; return c.f;
}
__device__ __forceinline__ unsigned short f2bf(float f) {
  union { float f; unsigned int i; } c; c.f = f;
  unsigned int x = c.i;
  return (unsigned short)((x + 0x7FFFu + ((x >> 16) & 1u)) >> 16);  // RNE
}

// ---- elementwise f32 -> bf16 cast ----
__global__ __launch_bounds__(256) void cast_bf16_kernel(
    const float* __restrict__ src, unsigned short* __restrict__ dst, long n) {
  long i = ((long)blockIdx.x * 256 + threadIdx.x) * 4;
  const long stride = (long)gridDim.x * 1024;
  for (; i < n; i += stride) {
    float4 v = *(const float4*)(src + i);
    ushort4 o;
    o.x = f2bf(v.x); o.y = f2bf(v.y); o.z = f2bf(v.z); o.w = f2bf(v.w);
    *(ushort4*)(dst + i) = o;
  }
}

// ---- async global->LDS 16B (wave-uniform base + lane*16 layout) ----
__device__ __forceinline__ void async_cp16(const void* g, void* l) {
  __builtin_amdgcn_global_load_lds((const __attribute__((address_space(1))) void*)g,
                                   (__attribute__((address_space(3))) void*)l, 16, 0, 0);
}

// ---------------------------------------------------------------------------
// 2-phase double-buffered bf16 GEMM:  C[M,N] = A[M,K] @ B[N,K]^T
//   BK = 64, LDS double buffer; stage tile kt+1 BEFORE computing tile kt so
//   global_load_lds latency hides under ~64 MFMAs; one barrier per K-tile.
//   GROUPED: A rows are compact per-expert segments (256-aligned offsets in
//   offs[0..NEXP]); B = W + e*wstride. FUSE_SILU: C holds gate bf16; epilogue
//   computes silu(g)*v in place.
// ---------------------------------------------------------------------------
template <int BM, int BN, int WM, int WN, int WRITE_BF16, int FUSE_SILU, int GROUPED>
__global__ __launch_bounds__(WM * WN * 64, 2) void gemm2ph(
    const unsigned short* __restrict__ A,
    const unsigned short* __restrict__ W,
    void* __restrict__ Cv,
    const int* __restrict__ offs,
    int N, int K, size_t wstride) {
  constexpr int NTHR = WM * WN * 64;
  constexpr int TM = BM / WM;       // per-wave output rows
  constexpr int TN = BN / WN;       // per-wave output cols
  constexpr int AM = TM / 16;
  constexpr int AN = TN / 16;
  constexpr int LA = BM * 8 / NTHR; // 16B staging chunks per thread (A)
  constexpr int LB = BN * 8 / NTHR;

  // ---- T1: bijective XCD-aware block swizzle (m204) ----
  const int gx = gridDim.x;
  const int nwg = gx * gridDim.y;
  int bid = blockIdx.y * gx + blockIdx.x;
  {
    const int q = nwg >> 3, r = nwg & 7;
    const int x = bid & 7, l = bid >> 3;
    bid = (x < r ? x * (q + 1) : r * (q + 1) + (x - r) * q) + l;
  }
  const int bx = bid % gx;
  const int by = bid / gx;

  const int row0 = bx * BM;
  const unsigned short* Bp;
  if constexpr (GROUPED) {
    if (row0 >= offs[NEXP]) return;   // uniform early-exit, before any barrier
    int e = 0;
#pragma unroll
    for (int i = 1; i < NEXP; ++i) e += (row0 >= offs[i]) ? 1 : 0;
    Bp = W + (size_t)e * wstride;
  } else {
    Bp = W;
  }

  __shared__ __align__(16) unsigned short As[2][BM * 64];
  __shared__ __align__(16) unsigned short Bs[2][BN * 64];

  const int tid = threadIdx.x;
  const int lane = tid & 63, wave = tid >> 6;
  const int wm = wave / WN, wn = wave % WN;
  const int lm = lane & 15, kq = lane >> 4;

  const long arow = row0;
  const long brow = (long)by * BN;

  // staging addresses: chunk c covers (row = c>>3, 16B k-chunk = c&7)
  const unsigned short* asrc[LA];
  unsigned short* adst[LA];
#pragma unroll
  for (int q = 0; q < LA; ++q) {
    const int c = q * NTHR + tid;
    asrc[q] = A + (arow + (c >> 3)) * (long)K + ((c & 7) << 3);
    adst[q] = &As[0][c * 8];
  }
  const unsigned short* bsrc[LB];
  unsigned short* bdst[LB];
#pragma unroll
  for (int q = 0; q < LB; ++q) {
    const int c = q * NTHR + tid;
    bsrc[q] = Bp + (brow + (c >> 3)) * (long)K + ((c & 7) << 3);
    bdst[q] = &Bs[0][c * 8];
  }

  f32x4 acc[AM][AN];
#pragma unroll
  for (int i = 0; i < AM; ++i)
#pragma unroll
    for (int j = 0; j < AN; ++j) acc[i][j] = (f32x4){0.f, 0.f, 0.f, 0.f};

  const int KT = K >> 6;

  // prologue: stage K-tile 0 into buf 0
#pragma unroll
  for (int q = 0; q < LA; ++q) async_cp16(asrc[q], adst[q]);
#pragma unroll
  for (int q = 0; q < LB; ++q) async_cp16(bsrc[q], bdst[q]);
  __syncthreads();

  for (int kt = 0; kt < KT; ++kt) {
    const int cur = kt & 1;
    // stage next K-tile into the other buffer FIRST (loads fly over compute;
    // that buffer's readers finished before the barrier that ended kt-1)
    if (kt + 1 < KT) {
      const int koff = (kt + 1) << 6;
      const int ao = (cur ^ 1) * (BM * 64);
      const int bo = (cur ^ 1) * (BN * 64);
#pragma unroll
      for (int q = 0; q < LA; ++q) async_cp16(asrc[q] + koff, adst[q] + ao);
#pragma unroll
      for (int q = 0; q < LB; ++q) async_cp16(bsrc[q] + koff, bdst[q] + bo);
    }
    const unsigned short* Ab = As[cur];
    const unsigned short* Bb = Bs[cur];
#pragma unroll
    for (int ks = 0; ks < 2; ++ks) {
      bf16x8 af[AM], bfr[AN];
#pragma unroll
      for (int mi = 0; mi < AM; ++mi)
        af[mi] = *(const bf16x8*)(Ab + (wm * TM + mi * 16 + lm) * 64 + ks * 32 + kq * 8);
#pragma unroll
      for (int ni = 0; ni < AN; ++ni)
        bfr[ni] = *(const bf16x8*)(Bb + (wn * TN + ni * 16 + lm) * 64 + ks * 32 + kq * 8);
#pragma unroll
      for (int mi = 0; mi < AM; ++mi)
#pragma unroll
        for (int ni = 0; ni < AN; ++ni)
          acc[mi][ni] = __builtin_amdgcn_mfma_f32_16x16x32_bf16(af[mi], bfr[ni],
                                                                acc[mi][ni], 0, 0, 0);
    }
    __syncthreads();  // drains vmcnt(0): next tile staged; lgkm: reads done
  }

  // epilogue — C/D layout: col = lane&15, row = (lane>>4)*4 + reg (verified)
  const long rbase = arow + wm * TM + kq * 4;
  const long cbase = brow + wn * TN + lm;
#pragma unroll
  for (int mi = 0; mi < AM; ++mi)
#pragma unroll
    for (int ni = 0; ni < AN; ++ni)
#pragma unroll
      for (int r = 0; r < 4; ++r) {
        const long row = rbase + mi * 16 + r;
        const long col = cbase + ni * 16;
        float v = acc[mi][ni][r];
        if constexpr (FUSE_SILU) {
          const float g = bf2f(((const unsigned short*)Cv)[row * N + col]);
          v = g / (1.f + expf(-g)) * v;
        }
        if constexpr (WRITE_BF16) ((unsigned short*)Cv)[row * N + col] = f2bf(v);
        else                      ((float*)Cv)[row * N + col] = v;
      }
}

// ---- rmsnorm: f32 in -> bf16 out, optional invrms export; D = 1024 ----
__global__ __launch_bounds__(256) void rmsnorm_kernel(
    const float* __restrict__ in, const float* __restrict__ w,
    unsigned short* __restrict__ out, float* __restrict__ invrms) {
  const int row = blockIdx.x;
  const int tid = threadIdx.x;
  const float4 xv = ((const float4*)(in + (long)row * DMODEL))[tid];
  float ss = xv.x * xv.x + xv.y * xv.y + xv.z * xv.z + xv.w * xv.w;
#pragma unroll
  for (int o = 32; o > 0; o >>= 1) ss += __shfl_xor(ss, o);
  __shared__ float red[4];
  if ((tid & 63) == 0) red[tid >> 6] = ss;
  __syncthreads();
  const float tot = red[0] + red[1] + red[2] + red[3];
  const float s = rsqrtf(tot * (1.f / DMODEL) + RMS_EPS);
  if (invrms != nullptr && tid == 0) invrms[row] = s;
  const float4 wv = ((const float4*)w)[tid];
  ushort4 o4;
  o4.x = f2bf(xv.x * s * wv.x);
  o4.y = f2bf(xv.y * s * wv.y);
  o4.z = f2bf(xv.z * s * wv.z);
  o4.w = f2bf(xv.w * s * wv.w);
  ((ushort4*)(out + (long)row * DMODEL))[tid] = o4;
}

// ---- fold router weight through W_in: Wr2[e,k] = sum_j Wr[e,j]*nw[j]*W_in[j,k]
__global__ __launch_bounds__(256) void router_prep_kernel(
    const float* __restrict__ Wr, const float* __restrict__ nw,
    const float* __restrict__ W_in, float* __restrict__ Wr2) {
  __shared__ float wr[NEXP * DMODEL];  // 32 KB
  const int tid = threadIdx.x;
  for (int i = tid; i < NEXP * DMODEL; i += 256) wr[i] = Wr[i] * nw[i & (DMODEL - 1)];
  __syncthreads();
  const int kl = tid & 127;
  const int eb = (tid >> 7) * 4;
  const int kg = blockIdx.x * 128 + kl;
  float a0 = 0.f, a1 = 0.f, a2 = 0.f, a3 = 0.f;
  for (int j = 0; j < DMODEL; ++j) {
    const float wij = W_in[(long)j * DMODEL + kg];
    a0 += wr[(eb + 0) * DMODEL + j] * wij;
    a1 += wr[(eb + 1) * DMODEL + j] * wij;
    a2 += wr[(eb + 2) * DMODEL + j] * wij;
    a3 += wr[(eb + 3) * DMODEL + j] * wij;
  }
  Wr2[(eb + 0) * DMODEL + kg] = a0;
  Wr2[(eb + 1) * DMODEL + kg] = a1;
  Wr2[(eb + 2) * DMODEL + kg] = a2;
  Wr2[(eb + 3) * DMODEL + kg] = a3;
}

// ---- router: fp32 logits, top-2, softmax; scatter into compact lists ----
__global__ __launch_bounds__(64) void router_kernel(
    const float* __restrict__ x, const float* __restrict__ Wr2,
    const float* __restrict__ bias, const float* __restrict__ invrms,
    int* __restrict__ cnt, int* __restrict__ tok, float* __restrict__ gv) {
  const int row = blockIdx.x;
  const int lane = threadIdx.x;
  const float* xr = x + (long)row * DMODEL;
  float p[NEXP] = {0.f, 0.f, 0.f, 0.f, 0.f, 0.f, 0.f, 0.f};
  for (int k = lane; k < DMODEL; k += 64) {
    const float xv = xr[k];
#pragma unroll
    for (int e = 0; e < NEXP; ++e) p[e] += xv * Wr2[e * DMODEL + k];
  }
#pragma unroll
  for (int o = 32; o > 0; o >>= 1)
#pragma unroll
    for (int e = 0; e < NEXP; ++e) p[e] += __shfl_xor(p[e], o);
  if (lane == 0) {
    const float s = invrms[row];
    float logit[NEXP];
    float b0 = -1e30f, b1 = -1e30f;
    int i0 = 0, i1 = 0;
#pragma unroll
    for (int e = 0; e < NEXP; ++e) {
      logit[e] = p[e] * s;
      const float be = logit[e] + bias[e];
      if (be > b0)      { b1 = b0; i1 = i0; b0 = be; i0 = e; }
      else if (be > b1) { b1 = be; i1 = e; }
    }
    const float l0 = logit[i0], l1 = logit[i1];
    const float m = fmaxf(l0, l1);
    const float e0 = expf(l0 - m), e1 = expf(l1 - m);
    const float inv = 1.f / (e0 + e1);
    const int s0 = atomicAdd(&cnt[i0], 1);
    tok[i0 * NT + s0] = row;
    gv[i0 * NT + s0] = e0 * inv;
    const int s1 = atomicAdd(&cnt[i1], 1);
    tok[i1 * NT + s1] = row;
    gv[i1 * NT + s1] = e1 * inv;
  }
}

// ---- pad counts to 256-multiples, prefix-sum offsets, fill pad slots ----
__global__ __launch_bounds__(256) void pad_kernel(
    const int* __restrict__ cnt, int* __restrict__ tok,
    int* __restrict__ pcnt, int* __restrict__ off) {
  __shared__ int sc[NEXP], sp[NEXP];
  const int tid = threadIdx.x;
  if (tid == 0) {
    int o = 0;
    for (int e = 0; e < NEXP; ++e) {
      const int c = cnt[e];
      const int p = (c + 255) & ~255;
      sc[e] = c; sp[e] = p;
      pcnt[e] = p; off[e] = o;
      o += p;
    }
    off[NEXP] = o;
  }
  __syncthreads();
  for (int e = 0; e < NEXP; ++e) {
    const int c = sc[e], p = sp[e];
    for (int s = c + tid; s < p; s += 256) tok[e * NT + s] = 0;
  }
}

// ---- gather compact A rows: Ac[r] = hb[tok[r]] (pads copy row 0) ----
__global__ __launch_bounds__(256) void gather_kernel(
    const unsigned short* __restrict__ hb, const int* __restrict__ tok,
    const int* __restrict__ offs, unsigned short* __restrict__ Ac) {
  const int r = blockIdx.x;
  if (r >= offs[NEXP]) return;
  int e = 0;
#pragma unroll
  for (int i = 1; i < NEXP; ++i) e += (r >= offs[i]) ? 1 : 0;
  const int src = tok[e * NT + (r - offs[e])];
  const ushort4* s4 = (const ushort4*)(hb + (long)src * DMODEL);
  ushort4* d4 = (ushort4*)(Ac + (long)r * DMODEL);
  d4[threadIdx.x] = s4[threadIdx.x];
}

// ---- acc[tok[s]] += gv[s] * rmsnorm(oe[off+s])*enorm_w[e]  (one expert) ----
__global__ __launch_bounds__(256) void expert_scatter(
    const float* __restrict__ oe, const float* __restrict__ enw,
    const int* __restrict__ tok, const float* __restrict__ gv,
    const int* __restrict__ cnt, const int* __restrict__ off,
    int e, float* __restrict__ acc) {
  const int s = blockIdx.x;
  if (s >= cnt[e]) return;
  const int row = tok[e * NT + s];
  const float g = gv[e * NT + s];
  const int tid = threadIdx.x;
  const float4 xv = ((const float4*)(oe + ((long)off[e] + s) * DMODEL))[tid];
  float ss = xv.x * xv.x + xv.y * xv.y + xv.z * xv.z + xv.w * xv.w;
#pragma unroll
  for (int o = 32; o > 0; o >>= 1) ss += __shfl_xor(ss, o);
  __shared__ float red[4];
  if ((tid & 63) == 0) red[tid >> 6] = ss;
  __syncthreads();
  const float tot = red[0] + red[1] + red[2] + red[3];
  const float sc = rsqrtf(tot * (1.f / DMODEL) + RMS_EPS) * g;
  const float4 wv = ((const float4*)enw)[tid];
  float4* ap = (float4*)(acc + (long)row * DMODEL) + tid;
  float4 a = *ap;
  a.x += xv.x * sc * wv.x;
  a.y += xv.y * sc * wv.y;
  a.z += xv.z * sc * wv.z;
  a.w += xv.w * sc * wv.w;
  *ap = a;
}

extern "C" void kernel_launch(void* const* d_in, const int* in_sizes, int n_in,
                              void* d_out, int out_size, void* d_ws, size_t ws_size,
                              hipStream_t stream) {
  (void)in_sizes; (void)n_in; (void)out_size; (void)ws_size;
  const float* s_in  = (const float*)d_in[0];
  const float* W_in  = (const float*)d_in[1];
  const float* innw  = (const float*)d_in[2];
  const float* Wr    = (const float*)d_in[3];
  const float* ebias = (const float*)d_in[4];
  const float* Wg    = (const float*)d_in[5];
  const float* Wu    = (const float*)d_in[6];
  const float* Wd    = (const float*)d_in[7];
  const float* enw   = (const float*)d_in[8];
  const float* outnw = (const float*)d_in[9];
  const float* W_out = (const float*)d_in[10];
  float* out = (float*)d_out;

  // ---- workspace layout (~527 MB) ----
  char* base = (char*)d_ws;
  size_t off_b = 0;
  auto alloc = [&](size_t bytes) -> char* {
    char* p = base + off_b;
    off_b += (bytes + 255) & ~(size_t)255;
    return p;
  };
  unsigned short* xb    = (unsigned short*)alloc((size_t)NT * DMODEL * 2);
  unsigned short* Winb  = (unsigned short*)alloc((size_t)DMODEL * DMODEL * 2);
  unsigned short* Wgb   = (unsigned short*)alloc((size_t)NEXP * DFF * DMODEL * 2);
  unsigned short* Wub   = (unsigned short*)alloc((size_t)NEXP * DFF * DMODEL * 2);
  unsigned short* Wdb   = (unsigned short*)alloc((size_t)NEXP * DMODEL * DFF * 2);
  unsigned short* Woutb = (unsigned short*)alloc((size_t)DMODEL * DMODEL * 2);
  float*          hpre  = (float*)alloc((size_t)NT * DMODEL * 4);
  unsigned short* hb    = (unsigned short*)alloc((size_t)NT * DMODEL * 2);
  float*          invr  = (float*)alloc((size_t)NT * 4);
  float*          Wr2   = (float*)alloc((size_t)NEXP * DMODEL * 4);
  int*            cnt   = (int*)alloc((size_t)NEXP * 4);
  int*            pcnt  = (int*)alloc((size_t)NEXP * 4);
  int*            offs  = (int*)alloc((size_t)(NEXP + 1) * 4);
  int*            tok   = (int*)alloc((size_t)NEXP * NT * 4);
  float*          gv    = (float*)alloc((size_t)NEXP * NT * 4);
  unsigned short* Ac    = (unsigned short*)alloc((size_t)MAXROWS * DMODEL * 2);
  unsigned short* Hc    = (unsigned short*)alloc((size_t)MAXROWS * DFF * 2);
  float*          oec   = (float*)alloc((size_t)MAXROWS * DMODEL * 4);
  // aliases: accb over hpre (dead after rmsnorm), yb over xb (dead after
  // in-projection GEMM)
  float*          accb  = hpre;
  unsigned short* yb    = xb;

  // ---- 1. casts + zero the slot counters ----
  hipMemsetAsync(cnt, 0, NEXP * 4, stream);
  cast_bf16_kernel<<<2048, 256, 0, stream>>>(s_in, xb, (long)NT * DMODEL);
  cast_bf16_kernel<<<2048, 256, 0, stream>>>(W_in, Winb, (long)DMODEL * DMODEL);
  cast_bf16_kernel<<<2048, 256, 0, stream>>>(Wg, Wgb, (long)NEXP * DFF * DMODEL);
  cast_bf16_kernel<<<2048, 256, 0, stream>>>(Wu, Wub, (long)NEXP * DFF * DMODEL);
  cast_bf16_kernel<<<2048, 256, 0, stream>>>(Wd, Wdb, (long)NEXP * DMODEL * DFF);
  cast_bf16_kernel<<<2048, 256, 0, stream>>>(W_out, Woutb, (long)DMODEL * DMODEL);

  // ---- 2. hpre = x @ W_in^T ; hb = rmsnorm(hpre)*innw (+invrms) ----
  gemm2ph<128, 128, 2, 2, 0, 0, 0><<<dim3(NT / 128, DMODEL / 128), 256, 0, stream>>>(
      xb, Winb, hpre, nullptr, DMODEL, DMODEL, 0);
  rmsnorm_kernel<<<NT, 256, 0, stream>>>(hpre, innw, hb, invr);
  hipMemsetAsync(accb, 0, (size_t)NT * DMODEL * 4, stream);

  // ---- 3. router + compaction ----
  router_prep_kernel<<<DMODEL / 128, 256, 0, stream>>>(Wr, innw, W_in, Wr2);
  router_kernel<<<NT, 64, 0, stream>>>(s_in, Wr2, ebias, invr, cnt, tok, gv);
  pad_kernel<<<1, 256, 0, stream>>>(cnt, tok, pcnt, offs);

  // ---- 4. gather compact A ----
  gather_kernel<<<MAXROWS, 256, 0, stream>>>(hb, tok, offs, Ac);

  // ---- 5/6. gate GEMM then up GEMM with in-place silu epilogue ----
  gemm2ph<256, 256, 2, 4, 1, 0, 1><<<dim3(MAXROWS / 256, DFF / 256), 512, 0, stream>>>(
      Ac, Wgb, Hc, offs, DFF, DMODEL, (size_t)DFF * DMODEL);
  gemm2ph<256, 256, 2, 4, 1, 1, 1><<<dim3(MAXROWS / 256, DFF / 256), 512, 0, stream>>>(
      Ac, Wub, Hc, offs, DFF, DMODEL, (size_t)DFF * DMODEL);

  // ---- 7. down projection (compact rows, f32 out; 128^2 / 2 blocks/CU) ----
  gemm2ph<128, 128, 2, 2, 0, 0, 1><<<dim3(MAXROWS / 128, DMODEL / 128), 256, 0, stream>>>(
      Hc, Wdb, oec, offs, DMODEL, DFF, (size_t)DMODEL * DFF);

  // ---- 8. per-expert scatter-accumulate (sequential => deterministic) ----
  for (int e = 0; e < NEXP; ++e)
    expert_scatter<<<NT, 256, 0, stream>>>(
        oec, enw + (size_t)e * DMODEL, tok, gv, cnt, offs, e, accb);

  // ---- 9. output projection ----
  rmsnorm_kernel<<<NT, 256, 0, stream>>>(accb, outnw, yb, nullptr);
  gemm2ph<128, 128, 2, 2, 0, 0, 0><<<dim3(NT / 128, DMODEL / 128), 256, 0, stream>>>(
      yb, Woutb, out, nullptr, DMODEL, DMODEL, 0);
}

// Round 2
// 1416.250 us; speedup vs baseline: 1.2700x; 1.2700x over previous
//
#include <hip/hip_runtime.h>

// ---------------------------------------------------------------------------
// MoEPredictor on MI355X (gfx950) — Round 5: 8-phase counted-vmcnt expert GEMM.
//
//  * gemm8ph<FUSED>: 256x(256 B-rows) tile, BK=64, 8 waves (2x4), dbuf=2,
//    K-half staging granularity (16 KB), schedule per tile tau:
//      q0(ks0,Nlo): ds 8af+2bf | stage B1(tau+1) | bar | lgkm0 | 16 MFMA | bar
//      q1(ks0,Nhi): ds 2bf     | stage A0(tau+2) | bar | lgkm0 | 16 MFMA | bar
//      q2(ks1,Nlo): ds 8af+2bf | stage B0(tau+2) | bar | lgkm0 | 16 MFMA | bar
//      q3(ks1,Nhi): ds 2bf     | stage A1(tau+2) | bar | lgkm0 | 16 MFMA
//                   | vmcnt(6) (counted, 3 half-tiles in flight) | bar
//    T2 swizzle: LDS slot kq ^= (row>>1)&3, applied on pre-swizzled global
//    source AND ds_read (linear global_load_lds dest). 2-way residual = free.
//    T5 setprio(1) around each MFMA cluster. T1 bijective XCD swizzle.
//  * FUSED=1: B-tile rows interleave Wg/Wu (32+32 per wave) so silu(g)*u is
//    computed in-register in the epilogue -> gate+up in ONE GEMM, Hc written
//    once.  FUSED=0: plain B^T (down proj), split-K=2 via gridDim.z, partial
//    sums into oec/oec2 (oec2 aliases dead Wgb), summed in expert_scatter.
//  * in/out projections keep the R1 gemm2ph 128^2 (small fry).
// ---------------------------------------------------------------------------

#define NT      8192
#define DMODEL  1024
#define DFF     4096
#define NEXP    8
#define MAXROWS (NT * 2 + NEXP * 256)  // 18432 padded compact rows max
#define RMS_EPS 1.1920928955078125e-07f  // jnp.finfo(float32).eps

typedef __attribute__((ext_vector_type(8))) short bf16x8;   // MFMA A/B frag
typedef __attribute__((ext_vector_type(4))) float f32x4;    // MFMA C/D frag

__device__ __forceinline__ float bf2f(unsigned short u) {
  union { unsigned int i; float f; } c; c.i = ((unsigned int)u) << 16; return c.f;
}
__device__ __forceinline__ unsigned short f2bf(float f) {
  union { float f; unsigned int i; } c; c.f = f;
  unsigned int x = c.i;
  return (unsigned short)((x + 0x7FFFu + ((x >> 16) & 1u)) >> 16);  // RNE
}

#define BARX() __builtin_amdgcn_s_barrier()
#define LGKM0() do { asm volatile("s_waitcnt lgkmcnt(0)" ::: "memory"); \
                     __builtin_amdgcn_sched_barrier(0); } while (0)
#define VMC(n)  do { asm volatile("s_waitcnt vmcnt(" #n ")" ::: "memory"); \
                     __builtin_amdgcn_sched_barrier(0); } while (0)

// ---- elementwise f32 -> bf16 cast ----
__global__ __launch_bounds__(256) void cast_bf16_kernel(
    const float* __restrict__ src, unsigned short* __restrict__ dst, long n) {
  long i = ((long)blockIdx.x * 256 + threadIdx.x) * 4;
  const long stride = (long)gridDim.x * 1024;
  for (; i < n; i += stride) {
    float4 v = *(const float4*)(src + i);
    ushort4 o;
    o.x = f2bf(v.x); o.y = f2bf(v.y); o.z = f2bf(v.z); o.w = f2bf(v.w);
    *(ushort4*)(dst + i) = o;
  }
}

// ---- async global->LDS 16B (wave-uniform base + lane*16 layout) ----
__device__ __forceinline__ void async_cp16(const void* g, void* l) {
  __builtin_amdgcn_global_load_lds((const __attribute__((address_space(1))) void*)g,
                                   (__attribute__((address_space(3))) void*)l, 16, 0, 0);
}

// ---------------------------------------------------------------------------
// 8-phase grouped GEMM, 256 rows x 256 B-rows x K, counted vmcnt.
// FUSED=1: Wg/Wu interleaved B, bf16 silu-combined out (ld = DFF, 128 cols).
// FUSED=0: plain B^T from W0, f32 out (ld = DMODEL, 256 cols), split-K via z.
// ---------------------------------------------------------------------------
template <int FUSED>
__global__ __launch_bounds__(512, 2) void gemm8ph(
    const unsigned short* __restrict__ A,
    const unsigned short* __restrict__ W0,   // Wg (fused) / Wd (plain)
    const unsigned short* __restrict__ W1,   // Wu (fused) / unused
    void* __restrict__ Cv, void* __restrict__ Cv2,
    const int* __restrict__ offs,
    int K, int KT, size_t wstride) {
  // ---- T1: bijective XCD-aware block swizzle (m204) on the x/y plane ----
  const int gx = gridDim.x;
  const int nwg = gx * gridDim.y;
  int bid = blockIdx.y * gx + blockIdx.x;
  {
    const int q = nwg >> 3, r = nwg & 7;
    const int x = bid & 7, l = bid >> 3;
    bid = (x < r ? x * (q + 1) : r * (q + 1) + (x - r) * q) + l;
  }
  const int bx = bid % gx, by = bid / gx;

  const int row0 = bx * 256;
  if (row0 >= offs[NEXP]) return;   // uniform early-exit before any barrier
  int e = 0;
#pragma unroll
  for (int i = 1; i < NEXP; ++i) e += (row0 >= offs[i]) ? 1 : 0;

  // LDS: 2 dbuf x {A,B} x 2 K-halves x [256 rows][32 k] bf16 = 128 KB
  // short-offsets: buf<<15 | isB<<14 | ks<<13 | row*32 | slot*8
  __shared__ __align__(16) unsigned short lds[65536];

  const int t = threadIdx.x;
  const int lane = t & 63;
  const int wave = t >> 6;
  const int wm = wave >> 2, wn = wave & 3;   // 2 x 4 waves
  const int lm = lane & 15, kq = lane >> 4;
  const int k0 = blockIdx.z * (KT << 6);     // split-K start (elements)

  // ---- staging setup: thread t, load q covers linear slot L = q*512+t ----
  // LDS slot (row = L>>2, slot = t&3) holds global k-quad kq' = slot ^ f(row),
  // f(row) = (row>>1)&3  (inverse-swizzled source, linear dest — rule 21).
  const unsigned short* aP[2];
  const unsigned short* bP[2];
  int dl[2];
#pragma unroll
  for (int q = 0; q < 2; ++q) {
    const int L = q * 512 + t;
    const int row = L >> 2;
    const int kp = (t & 3) ^ ((row >> 1) & 3);
    dl[q] = L * 8;                                    // shorts
    aP[q] = A + (size_t)(row0 + row) * K + kp * 8 + k0;
    if (FUSED) {
      const int f = by * 128 + ((row >> 6) << 5) + (row & 31);
      const unsigned short* wb = (row & 32) ? W1 : W0;
      bP[q] = wb + (size_t)e * wstride + (size_t)f * K + kp * 8 + k0;
    } else {
      bP[q] = W0 + (size_t)e * wstride + (size_t)(by * 256 + row) * K + kp * 8 + k0;
    }
  }

  // ---- ds_read offsets (shorts), swizzled: slot = kq ^ ((row>>1)&3) ----
  int afo[8], bfo[4];
#pragma unroll
  for (int mi = 0; mi < 8; ++mi) {
    const int r = wm * 128 + mi * 16 + lm;
    afo[mi] = r * 32 + ((kq ^ ((r >> 1) & 3)) << 3);
  }
#pragma unroll
  for (int ni = 0; ni < 4; ++ni) {
    const int r = wn * 64 + ni * 16 + lm;
    bfo[ni] = 16384 + r * 32 + ((kq ^ ((r >> 1) & 3)) << 3);
  }

  f32x4 acc[8][4];
#pragma unroll
  for (int i = 0; i < 8; ++i)
#pragma unroll
    for (int j = 0; j < 4; ++j) acc[i][j] = (f32x4){0.f, 0.f, 0.f, 0.f};

  auto STG = [&](int tau, int ks, int isB) {
    const int roff = ((tau & 1) << 15) + (isB << 14) + (ks << 13);
    const int koff = (tau << 6) + (ks << 5);
#pragma unroll
    for (int q = 0; q < 2; ++q)
      async_cp16((isB ? bP[q] : aP[q]) + koff, lds + roff + dl[q]);
  };

  // ---- prologue: tile0 {A0,B0,A1,B1} + tile1 {A0,B0,A1}; 3 halves in flight
  STG(0, 0, 0); STG(0, 0, 1); STG(0, 1, 0); STG(0, 1, 1);
  STG(1, 0, 0); STG(1, 0, 1); STG(1, 1, 0);
  VMC(6);
  BARX();

  for (int tau = 0; tau < KT; ++tau) {
    const int tb = (tau & 1) << 15;
    const bool s1 = (tau + 1 < KT), s2 = (tau + 2 < KT);
    bf16x8 af[8], bq0, bq1;

    // ---- q0: ks0, N-low ----
#pragma unroll
    for (int mi = 0; mi < 8; ++mi) af[mi] = *(const bf16x8*)(lds + tb + afo[mi]);
    bq0 = *(const bf16x8*)(lds + tb + bfo[0]);
    bq1 = *(const bf16x8*)(lds + tb + bfo[1]);
    if (s1) STG(tau + 1, 1, 1);                 // B1(tau+1) -> other buf
    BARX(); LGKM0();
    __builtin_amdgcn_s_setprio(1);
#pragma unroll
    for (int mi = 0; mi < 8; ++mi) {
      acc[mi][0] = __builtin_amdgcn_mfma_f32_16x16x32_bf16(af[mi], bq0, acc[mi][0], 0, 0, 0);
      acc[mi][1] = __builtin_amdgcn_mfma_f32_16x16x32_bf16(af[mi], bq1, acc[mi][1], 0, 0, 0);
    }
    __builtin_amdgcn_s_setprio(0);
    BARX();

    // ---- q1: ks0, N-high ----
    bq0 = *(const bf16x8*)(lds + tb + bfo[2]);
    bq1 = *(const bf16x8*)(lds + tb + bfo[3]);
    if (s2) STG(tau + 2, 0, 0);                 // A0(tau+2), A0 dead after q0
    BARX(); LGKM0();
    __builtin_amdgcn_s_setprio(1);
#pragma unroll
    for (int mi = 0; mi < 8; ++mi) {
      acc[mi][2] = __builtin_amdgcn_mfma_f32_16x16x32_bf16(af[mi], bq0, acc[mi][2], 0, 0, 0);
      acc[mi][3] = __builtin_amdgcn_mfma_f32_16x16x32_bf16(af[mi], bq1, acc[mi][3], 0, 0, 0);
    }
    __builtin_amdgcn_s_setprio(0);
    BARX();

    // ---- q2: ks1, N-low ----
#pragma unroll
    for (int mi = 0; mi < 8; ++mi) af[mi] = *(const bf16x8*)(lds + tb + 8192 + afo[mi]);
    bq0 = *(const bf16x8*)(lds + tb + 8192 + bfo[0]);
    bq1 = *(const bf16x8*)(lds + tb + 8192 + bfo[1]);
    if (s2) STG(tau + 2, 0, 1);                 // B0(tau+2), B0 dead after q1
    BARX(); LGKM0();
    __builtin_amdgcn_s_setprio(1);
#pragma unroll
    for (int mi = 0; mi < 8; ++mi) {
      acc[mi][0] = __builtin_amdgcn_mfma_f32_16x16x32_bf16(af[mi], bq0, acc[mi][0], 0, 0, 0);
      acc[mi][1] = __builtin_amdgcn_mfma_f32_16x16x32_bf16(af[mi], bq1, acc[mi][1], 0, 0, 0);
    }
    __builtin_amdgcn_s_setprio(0);
    BARX();

    // ---- q3: ks1, N-high ----
    bq0 = *(const bf16x8*)(lds + tb + 8192 + bfo[2]);
    bq1 = *(const bf16x8*)(lds + tb + 8192 + bfo[3]);
    if (s2) STG(tau + 2, 1, 0);                 // A1(tau+2), A1 dead after q2
    BARX(); LGKM0();
    __builtin_amdgcn_s_setprio(1);
#pragma unroll
    for (int mi = 0; mi < 8; ++mi) {
      acc[mi][2] = __builtin_amdgcn_mfma_f32_16x16x32_bf16(af[mi], bq0, acc[mi][2], 0, 0, 0);
      acc[mi][3] = __builtin_amdgcn_mfma_f32_16x16x32_bf16(af[mi], bq1, acc[mi][3], 0, 0, 0);
    }
    __builtin_amdgcn_s_setprio(0);
    // counted vmcnt: waits tile tau+1 complete, leaves tau+2's 3 halves flying
    if (tau + 3 <= KT) { VMC(6); }
    else if (tau + 2 == KT) { VMC(0); }
    BARX();
  }

  // ---- epilogue — C/D: row = +kq*4+rr, col = +lm (R0-verified mapping) ----
  const long rbase = (long)row0 + wm * 128 + kq * 4;
  if (FUSED) {
    unsigned short* Hc = (unsigned short*)Cv;
    const int cb = by * 128 + wn * 32 + lm;
#pragma unroll
    for (int mi = 0; mi < 8; ++mi)
#pragma unroll
      for (int ni = 0; ni < 2; ++ni)
#pragma unroll
        for (int rr = 0; rr < 4; ++rr) {
          const float g = acc[mi][ni][rr];
          const float u = acc[mi][ni + 2][rr];
          const float h = g / (1.f + expf(-g)) * u;
          Hc[(rbase + mi * 16 + rr) * (long)DFF + cb + ni * 16] = f2bf(h);
        }
  } else {
    float* Cp = blockIdx.z ? (float*)Cv2 : (float*)Cv;
    const int cb = by * 256 + wn * 64 + lm;
#pragma unroll
    for (int mi = 0; mi < 8; ++mi)
#pragma unroll
      for (int ni = 0; ni < 4; ++ni)
#pragma unroll
        for (int rr = 0; rr < 4; ++rr)
          Cp[(rbase + mi * 16 + rr) * (long)DMODEL + cb + ni * 16] = acc[mi][ni][rr];
  }
}

// ---------------------------------------------------------------------------
// 2-phase double-buffered bf16 GEMM (kept from R1 for in/out projections).
// ---------------------------------------------------------------------------
template <int BM, int BN, int WM, int WN, int WRITE_BF16, int FUSE_SILU, int GROUPED>
__global__ __launch_bounds__(WM * WN * 64, 2) void gemm2ph(
    const unsigned short* __restrict__ A,
    const unsigned short* __restrict__ W,
    void* __restrict__ Cv,
    const int* __restrict__ offs,
    int N, int K, size_t wstride) {
  constexpr int NTHR = WM * WN * 64;
  constexpr int TM = BM / WM;
  constexpr int TN = BN / WN;
  constexpr int AM = TM / 16;
  constexpr int AN = TN / 16;
  constexpr int LA = BM * 8 / NTHR;
  constexpr int LB = BN * 8 / NTHR;

  const int gx = gridDim.x;
  const int nwg = gx * gridDim.y;
  int bid = blockIdx.y * gx + blockIdx.x;
  {
    const int q = nwg >> 3, r = nwg & 7;
    const int x = bid & 7, l = bid >> 3;
    bid = (x < r ? x * (q + 1) : r * (q + 1) + (x - r) * q) + l;
  }
  const int bx = bid % gx;
  const int by = bid / gx;

  const int row0 = bx * BM;
  const unsigned short* Bp;
  if constexpr (GROUPED) {
    if (row0 >= offs[NEXP]) return;
    int e = 0;
#pragma unroll
    for (int i = 1; i < NEXP; ++i) e += (row0 >= offs[i]) ? 1 : 0;
    Bp = W + (size_t)e * wstride;
  } else {
    Bp = W;
  }

  __shared__ __align__(16) unsigned short As[2][BM * 64];
  __shared__ __align__(16) unsigned short Bs[2][BN * 64];

  const int tid = threadIdx.x;
  const int lane = tid & 63, wave = tid >> 6;
  const int wm = wave / WN, wn = wave % WN;
  const int lm = lane & 15, kq = lane >> 4;

  const long arow = row0;
  const long brow = (long)by * BN;

  const unsigned short* asrc[LA];
  unsigned short* adst[LA];
#pragma unroll
  for (int q = 0; q < LA; ++q) {
    const int c = q * NTHR + tid;
    asrc[q] = A + (arow + (c >> 3)) * (long)K + ((c & 7) << 3);
    adst[q] = &As[0][c * 8];
  }
  const unsigned short* bsrc[LB];
  unsigned short* bdst[LB];
#pragma unroll
  for (int q = 0; q < LB; ++q) {
    const int c = q * NTHR + tid;
    bsrc[q] = Bp + (brow + (c >> 3)) * (long)K + ((c & 7) << 3);
    bdst[q] = &Bs[0][c * 8];
  }

  f32x4 acc[AM][AN];
#pragma unroll
  for (int i = 0; i < AM; ++i)
#pragma unroll
    for (int j = 0; j < AN; ++j) acc[i][j] = (f32x4){0.f, 0.f, 0.f, 0.f};

  const int KT = K >> 6;

#pragma unroll
  for (int q = 0; q < LA; ++q) async_cp16(asrc[q], adst[q]);
#pragma unroll
  for (int q = 0; q < LB; ++q) async_cp16(bsrc[q], bdst[q]);
  __syncthreads();

  for (int kt = 0; kt < KT; ++kt) {
    const int cur = kt & 1;
    if (kt + 1 < KT) {
      const int koff = (kt + 1) << 6;
      const int ao = (cur ^ 1) * (BM * 64);
      const int bo = (cur ^ 1) * (BN * 64);
#pragma unroll
      for (int q = 0; q < LA; ++q) async_cp16(asrc[q] + koff, adst[q] + ao);
#pragma unroll
      for (int q = 0; q < LB; ++q) async_cp16(bsrc[q] + koff, bdst[q] + bo);
    }
    const unsigned short* Ab = As[cur];
    const unsigned short* Bb = Bs[cur];
#pragma unroll
    for (int ks = 0; ks < 2; ++ks) {
      bf16x8 af[AM], bfr[AN];
#pragma unroll
      for (int mi = 0; mi < AM; ++mi)
        af[mi] = *(const bf16x8*)(Ab + (wm * TM + mi * 16 + lm) * 64 + ks * 32 + kq * 8);
#pragma unroll
      for (int ni = 0; ni < AN; ++ni)
        bfr[ni] = *(const bf16x8*)(Bb + (wn * TN + ni * 16 + lm) * 64 + ks * 32 + kq * 8);
#pragma unroll
      for (int mi = 0; mi < AM; ++mi)
#pragma unroll
        for (int ni = 0; ni < AN; ++ni)
          acc[mi][ni] = __builtin_amdgcn_mfma_f32_16x16x32_bf16(af[mi], bfr[ni],
                                                                acc[mi][ni], 0, 0, 0);
    }
    __syncthreads();
  }

  const long rbase = arow + wm * TM + kq * 4;
  const long cbase = brow + wn * TN + lm;
#pragma unroll
  for (int mi = 0; mi < AM; ++mi)
#pragma unroll
    for (int ni = 0; ni < AN; ++ni)
#pragma unroll
      for (int r = 0; r < 4; ++r) {
        const long row = rbase + mi * 16 + r;
        const long col = cbase + ni * 16;
        float v = acc[mi][ni][r];
        if constexpr (FUSE_SILU) {
          const float g = bf2f(((const unsigned short*)Cv)[row * N + col]);
          v = g / (1.f + expf(-g)) * v;
        }
        if constexpr (WRITE_BF16) ((unsigned short*)Cv)[row * N + col] = f2bf(v);
        else                      ((float*)Cv)[row * N + col] = v;
      }
}

// ---- rmsnorm: f32 in -> bf16 out, optional invrms export; D = 1024 ----
__global__ __launch_bounds__(256) void rmsnorm_kernel(
    const float* __restrict__ in, const float* __restrict__ w,
    unsigned short* __restrict__ out, float* __restrict__ invrms) {
  const int row = blockIdx.x;
  const int tid = threadIdx.x;
  const float4 xv = ((const float4*)(in + (long)row * DMODEL))[tid];
  float ss = xv.x * xv.x + xv.y * xv.y + xv.z * xv.z + xv.w * xv.w;
#pragma unroll
  for (int o = 32; o > 0; o >>= 1) ss += __shfl_xor(ss, o);
  __shared__ float red[4];
  if ((tid & 63) == 0) red[tid >> 6] = ss;
  __syncthreads();
  const float tot = red[0] + red[1] + red[2] + red[3];
  const float s = rsqrtf(tot * (1.f / DMODEL) + RMS_EPS);
  if (invrms != nullptr && tid == 0) invrms[row] = s;
  const float4 wv = ((const float4*)w)[tid];
  ushort4 o4;
  o4.x = f2bf(xv.x * s * wv.x);
  o4.y = f2bf(xv.y * s * wv.y);
  o4.z = f2bf(xv.z * s * wv.z);
  o4.w = f2bf(xv.w * s * wv.w);
  ((ushort4*)(out + (long)row * DMODEL))[tid] = o4;
}

// ---- fold router weight through W_in: Wr2[e,k] = sum_j Wr[e,j]*nw[j]*W_in[j,k]
__global__ __launch_bounds__(256) void router_prep_kernel(
    const float* __restrict__ Wr, const float* __restrict__ nw,
    const float* __restrict__ W_in, float* __restrict__ Wr2) {
  __shared__ float wr[NEXP * DMODEL];  // 32 KB
  const int tid = threadIdx.x;
  for (int i = tid; i < NEXP * DMODEL; i += 256) wr[i] = Wr[i] * nw[i & (DMODEL - 1)];
  __syncthreads();
  const int kl = tid & 127;
  const int eb = (tid >> 7) * 4;
  const int kg = blockIdx.x * 128 + kl;
  float a0 = 0.f, a1 = 0.f, a2 = 0.f, a3 = 0.f;
  for (int j = 0; j < DMODEL; ++j) {
    const float wij = W_in[(long)j * DMODEL + kg];
    a0 += wr[(eb + 0) * DMODEL + j] * wij;
    a1 += wr[(eb + 1) * DMODEL + j] * wij;
    a2 += wr[(eb + 2) * DMODEL + j] * wij;
    a3 += wr[(eb + 3) * DMODEL + j] * wij;
  }
  Wr2[(eb + 0) * DMODEL + kg] = a0;
  Wr2[(eb + 1) * DMODEL + kg] = a1;
  Wr2[(eb + 2) * DMODEL + kg] = a2;
  Wr2[(eb + 3) * DMODEL + kg] = a3;
}

// ---- router: fp32 logits, top-2, softmax; scatter into compact lists ----
__global__ __launch_bounds__(64) void router_kernel(
    const float* __restrict__ x, const float* __restrict__ Wr2,
    const float* __restrict__ bias, const float* __restrict__ invrms,
    int* __restrict__ cnt, int* __restrict__ tok, float* __restrict__ gv) {
  const int row = blockIdx.x;
  const int lane = threadIdx.x;
  const float* xr = x + (long)row * DMODEL;
  float p[NEXP] = {0.f, 0.f, 0.f, 0.f, 0.f, 0.f, 0.f, 0.f};
  for (int k = lane; k < DMODEL; k += 64) {
    const float xv = xr[k];
#pragma unroll
    for (int e = 0; e < NEXP; ++e) p[e] += xv * Wr2[e * DMODEL + k];
  }
#pragma unroll
  for (int o = 32; o > 0; o >>= 1)
#pragma unroll
    for (int e = 0; e < NEXP; ++e) p[e] += __shfl_xor(p[e], o);
  if (lane == 0) {
    const float s = invrms[row];
    float logit[NEXP];
    float b0 = -1e30f, b1 = -1e30f;
    int i0 = 0, i1 = 0;
#pragma unroll
    for (int e = 0; e < NEXP; ++e) {
      logit[e] = p[e] * s;
      const float be = logit[e] + bias[e];
      if (be > b0)      { b1 = b0; i1 = i0; b0 = be; i0 = e; }
      else if (be > b1) { b1 = be; i1 = e; }
    }
    const float l0 = logit[i0], l1 = logit[i1];
    const float m = fmaxf(l0, l1);
    const float e0 = expf(l0 - m), e1 = expf(l1 - m);
    const float inv = 1.f / (e0 + e1);
    const int s0 = atomicAdd(&cnt[i0], 1);
    tok[i0 * NT + s0] = row;
    gv[i0 * NT + s0] = e0 * inv;
    const int s1 = atomicAdd(&cnt[i1], 1);
    tok[i1 * NT + s1] = row;
    gv[i1 * NT + s1] = e1 * inv;
  }
}

// ---- pad counts to 256-multiples, prefix-sum offsets, fill pad slots ----
__global__ __launch_bounds__(256) void pad_kernel(
    const int* __restrict__ cnt, int* __restrict__ tok,
    int* __restrict__ pcnt, int* __restrict__ off) {
  __shared__ int sc[NEXP], sp[NEXP];
  const int tid = threadIdx.x;
  if (tid == 0) {
    int o = 0;
    for (int e = 0; e < NEXP; ++e) {
      const int c = cnt[e];
      const int p = (c + 255) & ~255;
      sc[e] = c; sp[e] = p;
      pcnt[e] = p; off[e] = o;
      o += p;
    }
    off[NEXP] = o;
  }
  __syncthreads();
  for (int e = 0; e < NEXP; ++e) {
    const int c = sc[e], p = sp[e];
    for (int s = c + tid; s < p; s += 256) tok[e * NT + s] = 0;
  }
}

// ---- gather compact A rows: Ac[r] = hb[tok[r]] (pads copy row 0) ----
__global__ __launch_bounds__(256) void gather_kernel(
    const unsigned short* __restrict__ hb, const int* __restrict__ tok,
    const int* __restrict__ offs, unsigned short* __restrict__ Ac) {
  const int r = blockIdx.x;
  if (r >= offs[NEXP]) return;
  int e = 0;
#pragma unroll
  for (int i = 1; i < NEXP; ++i) e += (r >= offs[i]) ? 1 : 0;
  const int src = tok[e * NT + (r - offs[e])];
  const ushort4* s4 = (const ushort4*)(hb + (long)src * DMODEL);
  ushort4* d4 = (ushort4*)(Ac + (long)r * DMODEL);
  d4[threadIdx.x] = s4[threadIdx.x];
}

// ---- acc[tok[s]] += gv[s]*rmsnorm(oe0[r]+oe1[r])*enorm_w[e]  (one expert) ----
__global__ __launch_bounds__(256) void expert_scatter(
    const float* __restrict__ oe0, const float* __restrict__ oe1,
    const float* __restrict__ enw,
    const int* __restrict__ tok, const float* __restrict__ gv,
    const int* __restrict__ cnt, const int* __restrict__ off,
    int e, float* __restrict__ acc) {
  const int s = blockIdx.x;
  if (s >= cnt[e]) return;
  const int row = tok[e * NT + s];
  const float g = gv[e * NT + s];
  const int tid = threadIdx.x;
  const long idx = ((long)off[e] + s) * DMODEL;
  const float4 x0 = ((const float4*)(oe0 + idx))[tid];
  const float4 x1 = ((const float4*)(oe1 + idx))[tid];
  float4 xv;
  xv.x = x0.x + x1.x; xv.y = x0.y + x1.y; xv.z = x0.z + x1.z; xv.w = x0.w + x1.w;
  float ss = xv.x * xv.x + xv.y * xv.y + xv.z * xv.z + xv.w * xv.w;
#pragma unroll
  for (int o = 32; o > 0; o >>= 1) ss += __shfl_xor(ss, o);
  __shared__ float red[4];
  if ((tid & 63) == 0) red[tid >> 6] = ss;
  __syncthreads();
  const float tot = red[0] + red[1] + red[2] + red[3];
  const float sc = rsqrtf(tot * (1.f / DMODEL) + RMS_EPS) * g;
  const float4 wv = ((const float4*)enw)[tid];
  float4* ap = (float4*)(acc + (long)row * DMODEL) + tid;
  float4 a = *ap;
  a.x += xv.x * sc * wv.x;
  a.y += xv.y * sc * wv.y;
  a.z += xv.z * sc * wv.z;
  a.w += xv.w * sc * wv.w;
  *ap = a;
}

extern "C" void kernel_launch(void* const* d_in, const int* in_sizes, int n_in,
                              void* d_out, int out_size, void* d_ws, size_t ws_size,
                              hipStream_t stream) {
  (void)in_sizes; (void)n_in; (void)out_size; (void)ws_size;
  const float* s_in  = (const float*)d_in[0];
  const float* W_in  = (const float*)d_in[1];
  const float* innw  = (const float*)d_in[2];
  const float* Wr    = (const float*)d_in[3];
  const float* ebias = (const float*)d_in[4];
  const float* Wg    = (const float*)d_in[5];
  const float* Wu    = (const float*)d_in[6];
  const float* Wd    = (const float*)d_in[7];
  const float* enw   = (const float*)d_in[8];
  const float* outnw = (const float*)d_in[9];
  const float* W_out = (const float*)d_in[10];
  float* out = (float*)d_out;

  // ---- workspace layout (~527 MB) ----
  char* base = (char*)d_ws;
  size_t off_b = 0;
  auto alloc = [&](size_t bytes) -> char* {
    char* p = base + off_b;
    off_b += (bytes + 255) & ~(size_t)255;
    return p;
  };
  unsigned short* xb    = (unsigned short*)alloc((size_t)NT * DMODEL * 2);
  unsigned short* Winb  = (unsigned short*)alloc((size_t)DMODEL * DMODEL * 2);
  unsigned short* Wgb   = (unsigned short*)alloc((size_t)NEXP * DFF * DMODEL * 2);
  unsigned short* Wub   = (unsigned short*)alloc((size_t)NEXP * DFF * DMODEL * 2);
  unsigned short* Wdb   = (unsigned short*)alloc((size_t)NEXP * DMODEL * DFF * 2);
  unsigned short* Woutb = (unsigned short*)alloc((size_t)DMODEL * DMODEL * 2);
  float*          hpre  = (float*)alloc((size_t)NT * DMODEL * 4);
  unsigned short* hb    = (unsigned short*)alloc((size_t)NT * DMODEL * 2);
  float*          invr  = (float*)alloc((size_t)NT * 4);
  float*          Wr2   = (float*)alloc((size_t)NEXP * DMODEL * 4);
  int*            cnt   = (int*)alloc((size_t)NEXP * 4);
  int*            pcnt  = (int*)alloc((size_t)NEXP * 4);
  int*            offs  = (int*)alloc((size_t)(NEXP + 1) * 4);
  int*            tok   = (int*)alloc((size_t)NEXP * NT * 4);
  float*          gv    = (float*)alloc((size_t)NEXP * NT * 4);
  unsigned short* Ac    = (unsigned short*)alloc((size_t)MAXROWS * DMODEL * 2);
  unsigned short* Hc    = (unsigned short*)alloc((size_t)MAXROWS * DFF * 2);
  float*          oec   = (float*)alloc((size_t)MAXROWS * DMODEL * 4);
  // aliases: accb over hpre (dead after rmsnorm); yb over xb (dead after
  // in-projection); oec2 (split-K partial 1, 75.5 MB) over Wgb+Wub (dead
  // after the fused gate/up GEMM).
  float*          accb  = hpre;
  unsigned short* yb    = xb;
  float*          oec2  = (float*)Wgb;

  // ---- 1. casts + zero the slot counters ----
  hipMemsetAsync(cnt, 0, NEXP * 4, stream);
  cast_bf16_kernel<<<2048, 256, 0, stream>>>(s_in, xb, (long)NT * DMODEL);
  cast_bf16_kernel<<<2048, 256, 0, stream>>>(W_in, Winb, (long)DMODEL * DMODEL);
  cast_bf16_kernel<<<2048, 256, 0, stream>>>(Wg, Wgb, (long)NEXP * DFF * DMODEL);
  cast_bf16_kernel<<<2048, 256, 0, stream>>>(Wu, Wub, (long)NEXP * DFF * DMODEL);
  cast_bf16_kernel<<<2048, 256, 0, stream>>>(Wd, Wdb, (long)NEXP * DMODEL * DFF);
  cast_bf16_kernel<<<2048, 256, 0, stream>>>(W_out, Woutb, (long)DMODEL * DMODEL);

  // ---- 2. hpre = x @ W_in^T ; hb = rmsnorm(hpre)*innw (+invrms) ----
  gemm2ph<128, 128, 2, 2, 0, 0, 0><<<dim3(NT / 128, DMODEL / 128), 256, 0, stream>>>(
      xb, Winb, hpre, nullptr, DMODEL, DMODEL, 0);
  rmsnorm_kernel<<<NT, 256, 0, stream>>>(hpre, innw, hb, invr);
  hipMemsetAsync(accb, 0, (size_t)NT * DMODEL * 4, stream);

  // ---- 3. router + compaction ----
  router_prep_kernel<<<DMODEL / 128, 256, 0, stream>>>(Wr, innw, W_in, Wr2);
  router_kernel<<<NT, 64, 0, stream>>>(s_in, Wr2, ebias, invr, cnt, tok, gv);
  pad_kernel<<<1, 256, 0, stream>>>(cnt, tok, pcnt, offs);

  // ---- 4. gather compact A ----
  gather_kernel<<<MAXROWS, 256, 0, stream>>>(hb, tok, offs, Ac);

  // ---- 5. FUSED gate+up GEMM: Hc = silu(Ac@Wg^T) * (Ac@Wu^T), one pass ----
  gemm8ph<1><<<dim3(MAXROWS / 256, DFF / 128), 512, 0, stream>>>(
      Ac, Wgb, Wub, Hc, nullptr, offs, DMODEL, DMODEL / 64, (size_t)DFF * DMODEL);

  // ---- 6. down projection, split-K=2 (z: k in [0,2048) / [2048,4096)) ----
  gemm8ph<0><<<dim3(MAXROWS / 256, DMODEL / 256, 2), 512, 0, stream>>>(
      Hc, Wdb, nullptr, oec, oec2, offs, DFF, 32, (size_t)DMODEL * DFF);

  // ---- 7. per-expert scatter-accumulate (sequential => deterministic) ----
  for (int e = 0; e < NEXP; ++e)
    expert_scatter<<<NT, 256, 0, stream>>>(
        oec, oec2, enw + (size_t)e * DMODEL, tok, gv, cnt, offs, e, accb);

  // ---- 8. output projection ----
  rmsnorm_kernel<<<NT, 256, 0, stream>>>(accb, outnw, yb, nullptr);
  gemm2ph<128, 128, 2, 2, 0, 0, 0><<<dim3(NT / 128, DMODEL / 128), 256, 0, stream>>>(
      yb, Woutb, out, nullptr, DMODEL, DMODEL, 0);
}

// Round 3
// 1375.235 us; speedup vs baseline: 1.3079x; 1.0298x over previous
//
#include <hip/hip_runtime.h>

// ---------------------------------------------------------------------------
// MoEPredictor on MI355X (gfx950) — Round 6: all GEMMs on the 8-phase
// counted-vmcnt template; per-token fused combine epilogue.
//
//  * gemm8ph<FUSED,GROUPED>: 256x256 tile, BK=64, 8 waves (2x4), dbuf=2,
//    K-half staging, counted vmcnt(6), T2 swizzle (0 bank conflicts, R2-
//    verified), T5 setprio, T1 bijective XCD swizzle.
//      <1,1>: gate+up fused (Wg/Wu interleaved B, silu in epilogue)
//      <0,1>: down projection (grouped, split-K=2 partials)
//      <0,0>: dense in/out projections (M=8192)
//  * router writes per-token (expert0|expert1, slot0, slot1, g0, g1);
//    combine_kernel does: oe_e = oec[r_e]+oec2[r_e]; acc = sum_e g_e *
//    rmsnorm(oe_e)*enorm_w[e]; yb = bf16(rmsnorm(acc)*outnw) — one dispatch,
//    replacing 8x expert_scatter + memset + final rmsnorm. Deterministic.
// ---------------------------------------------------------------------------

#define NT      8192
#define DMODEL  1024
#define DFF     4096
#define NEXP    8
#define MAXROWS (NT * 2 + NEXP * 256)  // 18432 padded compact rows max
#define RMS_EPS 1.1920928955078125e-07f  // jnp.finfo(float32).eps

typedef __attribute__((ext_vector_type(8))) short bf16x8;   // MFMA A/B frag
typedef __attribute__((ext_vector_type(4))) float f32x4;    // MFMA C/D frag

__device__ __forceinline__ float bf2f(unsigned short u) {
  union { unsigned int i; float f; } c; c.i = ((unsigned int)u) << 16; return c.f;
}
__device__ __forceinline__ unsigned short f2bf(float f) {
  union { float f; unsigned int i; } c; c.f = f;
  unsigned int x = c.i;
  return (unsigned short)((x + 0x7FFFu + ((x >> 16) & 1u)) >> 16);  // RNE
}

#define BARX() __builtin_amdgcn_s_barrier()
#define LGKM0() do { asm volatile("s_waitcnt lgkmcnt(0)" ::: "memory"); \
                     __builtin_amdgcn_sched_barrier(0); } while (0)
#define VMC(n)  do { asm volatile("s_waitcnt vmcnt(" #n ")" ::: "memory"); \
                     __builtin_amdgcn_sched_barrier(0); } while (0)

// ---- elementwise f32 -> bf16 cast ----
__global__ __launch_bounds__(256) void cast_bf16_kernel(
    const float* __restrict__ src, unsigned short* __restrict__ dst, long n) {
  long i = ((long)blockIdx.x * 256 + threadIdx.x) * 4;
  const long stride = (long)gridDim.x * 1024;
  for (; i < n; i += stride) {
    float4 v = *(const float4*)(src + i);
    ushort4 o;
    o.x = f2bf(v.x); o.y = f2bf(v.y); o.z = f2bf(v.z); o.w = f2bf(v.w);
    *(ushort4*)(dst + i) = o;
  }
}

// ---- async global->LDS 16B (wave-uniform base + lane*16 layout) ----
__device__ __forceinline__ void async_cp16(const void* g, void* l) {
  __builtin_amdgcn_global_load_lds((const __attribute__((address_space(1))) void*)g,
                                   (__attribute__((address_space(3))) void*)l, 16, 0, 0);
}

// ---------------------------------------------------------------------------
// 8-phase GEMM, 256 rows x 256 B-rows x K, counted vmcnt.
// FUSED=1: Wg/Wu interleaved B, bf16 silu-combined out (ld = DFF, 128 cols).
// FUSED=0: plain B^T from W0, f32 out (ld = DMODEL), split-K via gridDim.z.
// GROUPED=0: dense A (no expert segments, e = 0, no early exit).
// ---------------------------------------------------------------------------
template <int FUSED, int GROUPED>
__global__ __launch_bounds__(512, 2) void gemm8ph(
    const unsigned short* __restrict__ A,
    const unsigned short* __restrict__ W0,   // Wg (fused) / Wd / W_in / W_out
    const unsigned short* __restrict__ W1,   // Wu (fused) / unused
    void* __restrict__ Cv, void* __restrict__ Cv2,
    const int* __restrict__ offs,
    int K, int KT, size_t wstride) {
  // ---- T1: bijective XCD-aware block swizzle (m204) on the x/y plane ----
  const int gx = gridDim.x;
  const int nwg = gx * gridDim.y;
  int bid = blockIdx.y * gx + blockIdx.x;
  {
    const int q = nwg >> 3, r = nwg & 7;
    const int x = bid & 7, l = bid >> 3;
    bid = (x < r ? x * (q + 1) : r * (q + 1) + (x - r) * q) + l;
  }
  const int bx = bid % gx, by = bid / gx;

  const int row0 = bx * 256;
  int e = 0;
  if constexpr (GROUPED) {
    if (row0 >= offs[NEXP]) return;   // uniform early-exit before any barrier
#pragma unroll
    for (int i = 1; i < NEXP; ++i) e += (row0 >= offs[i]) ? 1 : 0;
  }

  // LDS: 2 dbuf x {A,B} x 2 K-halves x [256 rows][32 k] bf16 = 128 KB
  // short-offsets: buf<<15 | isB<<14 | ks<<13 | row*32 | slot*8
  __shared__ __align__(16) unsigned short lds[65536];

  const int t = threadIdx.x;
  const int lane = t & 63;
  const int wave = t >> 6;
  const int wm = wave >> 2, wn = wave & 3;   // 2 x 4 waves
  const int lm = lane & 15, kq = lane >> 4;
  const int k0 = blockIdx.z * (KT << 6);     // split-K start (elements)

  // ---- staging setup: thread t, load q covers linear slot L = q*512+t ----
  // LDS slot (row = L>>2, slot = t&3) holds global k-quad kq' = slot ^ f(row),
  // f(row) = (row>>1)&3  (inverse-swizzled source, linear dest — rule 21).
  const unsigned short* aP[2];
  const unsigned short* bP[2];
  int dl[2];
#pragma unroll
  for (int q = 0; q < 2; ++q) {
    const int L = q * 512 + t;
    const int row = L >> 2;
    const int kp = (t & 3) ^ ((row >> 1) & 3);
    dl[q] = L * 8;                                    // shorts
    aP[q] = A + (size_t)(row0 + row) * K + kp * 8 + k0;
    if (FUSED) {
      const int f = by * 128 + ((row >> 6) << 5) + (row & 31);
      const unsigned short* wb = (row & 32) ? W1 : W0;
      bP[q] = wb + (size_t)e * wstride + (size_t)f * K + kp * 8 + k0;
    } else {
      bP[q] = W0 + (size_t)e * wstride + (size_t)(by * 256 + row) * K + kp * 8 + k0;
    }
  }

  // ---- ds_read offsets (shorts), swizzled: slot = kq ^ ((row>>1)&3) ----
  int afo[8], bfo[4];
#pragma unroll
  for (int mi = 0; mi < 8; ++mi) {
    const int r = wm * 128 + mi * 16 + lm;
    afo[mi] = r * 32 + ((kq ^ ((r >> 1) & 3)) << 3);
  }
#pragma unroll
  for (int ni = 0; ni < 4; ++ni) {
    const int r = wn * 64 + ni * 16 + lm;
    bfo[ni] = 16384 + r * 32 + ((kq ^ ((r >> 1) & 3)) << 3);
  }

  f32x4 acc[8][4];
#pragma unroll
  for (int i = 0; i < 8; ++i)
#pragma unroll
    for (int j = 0; j < 4; ++j) acc[i][j] = (f32x4){0.f, 0.f, 0.f, 0.f};

  auto STG = [&](int tau, int ks, int isB) {
    const int roff = ((tau & 1) << 15) + (isB << 14) + (ks << 13);
    const int koff = (tau << 6) + (ks << 5);
#pragma unroll
    for (int q = 0; q < 2; ++q)
      async_cp16((isB ? bP[q] : aP[q]) + koff, lds + roff + dl[q]);
  };

  // ---- prologue: tile0 {A0,B0,A1,B1} + tile1 {A0,B0,A1}; 3 halves in flight
  STG(0, 0, 0); STG(0, 0, 1); STG(0, 1, 0); STG(0, 1, 1);
  STG(1, 0, 0); STG(1, 0, 1); STG(1, 1, 0);
  VMC(6);
  BARX();

  for (int tau = 0; tau < KT; ++tau) {
    const int tb = (tau & 1) << 15;
    const bool s1 = (tau + 1 < KT), s2 = (tau + 2 < KT);
    bf16x8 af[8], bq0, bq1;

    // ---- q0: ks0, N-low ----
#pragma unroll
    for (int mi = 0; mi < 8; ++mi) af[mi] = *(const bf16x8*)(lds + tb + afo[mi]);
    bq0 = *(const bf16x8*)(lds + tb + bfo[0]);
    bq1 = *(const bf16x8*)(lds + tb + bfo[1]);
    if (s1) STG(tau + 1, 1, 1);                 // B1(tau+1) -> other buf
    BARX(); LGKM0();
    __builtin_amdgcn_s_setprio(1);
#pragma unroll
    for (int mi = 0; mi < 8; ++mi) {
      acc[mi][0] = __builtin_amdgcn_mfma_f32_16x16x32_bf16(af[mi], bq0, acc[mi][0], 0, 0, 0);
      acc[mi][1] = __builtin_amdgcn_mfma_f32_16x16x32_bf16(af[mi], bq1, acc[mi][1], 0, 0, 0);
    }
    __builtin_amdgcn_s_setprio(0);
    BARX();

    // ---- q1: ks0, N-high ----
    bq0 = *(const bf16x8*)(lds + tb + bfo[2]);
    bq1 = *(const bf16x8*)(lds + tb + bfo[3]);
    if (s2) STG(tau + 2, 0, 0);                 // A0(tau+2), A0 dead after q0
    BARX(); LGKM0();
    __builtin_amdgcn_s_setprio(1);
#pragma unroll
    for (int mi = 0; mi < 8; ++mi) {
      acc[mi][2] = __builtin_amdgcn_mfma_f32_16x16x32_bf16(af[mi], bq0, acc[mi][2], 0, 0, 0);
      acc[mi][3] = __builtin_amdgcn_mfma_f32_16x16x32_bf16(af[mi], bq1, acc[mi][3], 0, 0, 0);
    }
    __builtin_amdgcn_s_setprio(0);
    BARX();

    // ---- q2: ks1, N-low ----
#pragma unroll
    for (int mi = 0; mi < 8; ++mi) af[mi] = *(const bf16x8*)(lds + tb + 8192 + afo[mi]);
    bq0 = *(const bf16x8*)(lds + tb + 8192 + bfo[0]);
    bq1 = *(const bf16x8*)(lds + tb + 8192 + bfo[1]);
    if (s2) STG(tau + 2, 0, 1);                 // B0(tau+2), B0 dead after q1
    BARX(); LGKM0();
    __builtin_amdgcn_s_setprio(1);
#pragma unroll
    for (int mi = 0; mi < 8; ++mi) {
      acc[mi][0] = __builtin_amdgcn_mfma_f32_16x16x32_bf16(af[mi], bq0, acc[mi][0], 0, 0, 0);
      acc[mi][1] = __builtin_amdgcn_mfma_f32_16x16x32_bf16(af[mi], bq1, acc[mi][1], 0, 0, 0);
    }
    __builtin_amdgcn_s_setprio(0);
    BARX();

    // ---- q3: ks1, N-high ----
    bq0 = *(const bf16x8*)(lds + tb + 8192 + bfo[2]);
    bq1 = *(const bf16x8*)(lds + tb + 8192 + bfo[3]);
    if (s2) STG(tau + 2, 1, 0);                 // A1(tau+2), A1 dead after q2
    BARX(); LGKM0();
    __builtin_amdgcn_s_setprio(1);
#pragma unroll
    for (int mi = 0; mi < 8; ++mi) {
      acc[mi][2] = __builtin_amdgcn_mfma_f32_16x16x32_bf16(af[mi], bq0, acc[mi][2], 0, 0, 0);
      acc[mi][3] = __builtin_amdgcn_mfma_f32_16x16x32_bf16(af[mi], bq1, acc[mi][3], 0, 0, 0);
    }
    __builtin_amdgcn_s_setprio(0);
    // counted vmcnt: waits tile tau+1 complete, leaves tau+2's 3 halves flying
    if (tau + 3 <= KT) { VMC(6); }
    else if (tau + 2 == KT) { VMC(0); }
    BARX();
  }

  // ---- epilogue — C/D: row = +kq*4+rr, col = +lm (verified mapping) ----
  const long rbase = (long)row0 + wm * 128 + kq * 4;
  if (FUSED) {
    unsigned short* Hc = (unsigned short*)Cv;
    const int cb = by * 128 + wn * 32 + lm;
#pragma unroll
    for (int mi = 0; mi < 8; ++mi)
#pragma unroll
      for (int ni = 0; ni < 2; ++ni)
#pragma unroll
        for (int rr = 0; rr < 4; ++rr) {
          const float g = acc[mi][ni][rr];
          const float u = acc[mi][ni + 2][rr];
          const float h = g / (1.f + expf(-g)) * u;
          Hc[(rbase + mi * 16 + rr) * (long)DFF + cb + ni * 16] = f2bf(h);
        }
  } else {
    float* Cp = blockIdx.z ? (float*)Cv2 : (float*)Cv;
    const int cb = by * 256 + wn * 64 + lm;
#pragma unroll
    for (int mi = 0; mi < 8; ++mi)
#pragma unroll
      for (int ni = 0; ni < 4; ++ni)
#pragma unroll
        for (int rr = 0; rr < 4; ++rr)
          Cp[(rbase + mi * 16 + rr) * (long)DMODEL + cb + ni * 16] = acc[mi][ni][rr];
  }
}

// ---- rmsnorm: f32 in -> bf16 out, optional invrms export; D = 1024 ----
__global__ __launch_bounds__(256) void rmsnorm_kernel(
    const float* __restrict__ in, const float* __restrict__ w,
    unsigned short* __restrict__ out, float* __restrict__ invrms) {
  const int row = blockIdx.x;
  const int tid = threadIdx.x;
  const float4 xv = ((const float4*)(in + (long)row * DMODEL))[tid];
  float ss = xv.x * xv.x + xv.y * xv.y + xv.z * xv.z + xv.w * xv.w;
#pragma unroll
  for (int o = 32; o > 0; o >>= 1) ss += __shfl_xor(ss, o);
  __shared__ float red[4];
  if ((tid & 63) == 0) red[tid >> 6] = ss;
  __syncthreads();
  const float tot = red[0] + red[1] + red[2] + red[3];
  const float s = rsqrtf(tot * (1.f / DMODEL) + RMS_EPS);
  if (invrms != nullptr && tid == 0) invrms[row] = s;
  const float4 wv = ((const float4*)w)[tid];
  ushort4 o4;
  o4.x = f2bf(xv.x * s * wv.x);
  o4.y = f2bf(xv.y * s * wv.y);
  o4.z = f2bf(xv.z * s * wv.z);
  o4.w = f2bf(xv.w * s * wv.w);
  ((ushort4*)(out + (long)row * DMODEL))[tid] = o4;
}

// ---- fold router weight through W_in: Wr2[e,k] = sum_j Wr[e,j]*nw[j]*W_in[j,k]
__global__ __launch_bounds__(256) void router_prep_kernel(
    const float* __restrict__ Wr, const float* __restrict__ nw,
    const float* __restrict__ W_in, float* __restrict__ Wr2) {
  __shared__ float wr[NEXP * DMODEL];  // 32 KB
  const int tid = threadIdx.x;
  for (int i = tid; i < NEXP * DMODEL; i += 256) wr[i] = Wr[i] * nw[i & (DMODEL - 1)];
  __syncthreads();
  const int kl = tid & 127;
  const int eb = (tid >> 7) * 4;
  const int kg = blockIdx.x * 128 + kl;
  float a0 = 0.f, a1 = 0.f, a2 = 0.f, a3 = 0.f;
  for (int j = 0; j < DMODEL; ++j) {
    const float wij = W_in[(long)j * DMODEL + kg];
    a0 += wr[(eb + 0) * DMODEL + j] * wij;
    a1 += wr[(eb + 1) * DMODEL + j] * wij;
    a2 += wr[(eb + 2) * DMODEL + j] * wij;
    a3 += wr[(eb + 3) * DMODEL + j] * wij;
  }
  Wr2[(eb + 0) * DMODEL + kg] = a0;
  Wr2[(eb + 1) * DMODEL + kg] = a1;
  Wr2[(eb + 2) * DMODEL + kg] = a2;
  Wr2[(eb + 3) * DMODEL + kg] = a3;
}

// ---- router: fp32 logits, top-2, softmax; compact lists + per-token maps ----
__global__ __launch_bounds__(64) void router_kernel(
    const float* __restrict__ x, const float* __restrict__ Wr2,
    const float* __restrict__ bias, const float* __restrict__ invrms,
    int* __restrict__ cnt, int* __restrict__ tok,
    int* __restrict__ te, int2* __restrict__ ts, float2* __restrict__ tg) {
  const int row = blockIdx.x;
  const int lane = threadIdx.x;
  const float* xr = x + (long)row * DMODEL;
  float p[NEXP] = {0.f, 0.f, 0.f, 0.f, 0.f, 0.f, 0.f, 0.f};
  for (int k = lane; k < DMODEL; k += 64) {
    const float xv = xr[k];
#pragma unroll
    for (int e = 0; e < NEXP; ++e) p[e] += xv * Wr2[e * DMODEL + k];
  }
#pragma unroll
  for (int o = 32; o > 0; o >>= 1)
#pragma unroll
    for (int e = 0; e < NEXP; ++e) p[e] += __shfl_xor(p[e], o);
  if (lane == 0) {
    const float s = invrms[row];
    float logit[NEXP];
    float b0 = -1e30f, b1 = -1e30f;
    int i0 = 0, i1 = 0;
#pragma unroll
    for (int e = 0; e < NEXP; ++e) {
      logit[e] = p[e] * s;
      const float be = logit[e] + bias[e];
      if (be > b0)      { b1 = b0; i1 = i0; b0 = be; i0 = e; }
      else if (be > b1) { b1 = be; i1 = e; }
    }
    const float l0 = logit[i0], l1 = logit[i1];
    const float m = fmaxf(l0, l1);
    const float e0 = expf(l0 - m), e1 = expf(l1 - m);
    const float inv = 1.f / (e0 + e1);
    const int s0 = atomicAdd(&cnt[i0], 1);
    tok[i0 * NT + s0] = row;
    const int s1 = atomicAdd(&cnt[i1], 1);
    tok[i1 * NT + s1] = row;
    te[row] = i0 | (i1 << 8);
    ts[row] = make_int2(s0, s1);
    tg[row] = make_float2(e0 * inv, e1 * inv);
  }
}

// ---- pad counts to 256-multiples, prefix-sum offsets, fill pad slots ----
__global__ __launch_bounds__(256) void pad_kernel(
    const int* __restrict__ cnt, int* __restrict__ tok, int* __restrict__ off) {
  __shared__ int sc[NEXP], sp[NEXP];
  const int tid = threadIdx.x;
  if (tid == 0) {
    int o = 0;
    for (int e = 0; e < NEXP; ++e) {
      const int c = cnt[e];
      const int p = (c + 255) & ~255;
      sc[e] = c; sp[e] = p;
      off[e] = o;
      o += p;
    }
    off[NEXP] = o;
  }
  __syncthreads();
  for (int e = 0; e < NEXP; ++e) {
    const int c = sc[e], p = sp[e];
    for (int s = c + tid; s < p; s += 256) tok[e * NT + s] = 0;
  }
}

// ---- gather compact A rows: Ac[r] = hb[tok[r]] (pads copy row 0) ----
__global__ __launch_bounds__(256) void gather_kernel(
    const unsigned short* __restrict__ hb, const int* __restrict__ tok,
    const int* __restrict__ offs, unsigned short* __restrict__ Ac) {
  const int r = blockIdx.x;
  if (r >= offs[NEXP]) return;
  int e = 0;
#pragma unroll
  for (int i = 1; i < NEXP; ++i) e += (r >= offs[i]) ? 1 : 0;
  const int src = tok[e * NT + (r - offs[e])];
  const ushort4* s4 = (const ushort4*)(hb + (long)src * DMODEL);
  ushort4* d4 = (ushort4*)(Ac + (long)r * DMODEL);
  d4[threadIdx.x] = s4[threadIdx.x];
}

// ---- per-token combine: expert rmsnorm + gates + final rmsnorm, one pass ----
// yb[row] = bf16( rmsnorm( sum_e g_e * rmsnorm(oec[r_e]+oec2[r_e]) * enw[e] )
//                 * outnw )
__global__ __launch_bounds__(256) void combine_kernel(
    const float* __restrict__ oe0, const float* __restrict__ oe1,
    const float* __restrict__ enw, const float* __restrict__ outnw,
    const int* __restrict__ offs, const int* __restrict__ te,
    const int2* __restrict__ ts, const float2* __restrict__ tg,
    unsigned short* __restrict__ yb) {
  const int row = blockIdx.x;
  const int tid = threadIdx.x;
  const int pe = te[row];
  const int e0 = pe & 0xff, e1 = (pe >> 8) & 0xff;
  const int2 sl = ts[row];
  const float2 g = tg[row];
  const long r0 = (long)(offs[e0] + sl.x) * DMODEL;
  const long r1 = (long)(offs[e1] + sl.y) * DMODEL;

  float4 a = ((const float4*)(oe0 + r0))[tid];
  {
    const float4 b = ((const float4*)(oe1 + r0))[tid];
    a.x += b.x; a.y += b.y; a.z += b.z; a.w += b.w;
  }
  float4 c = ((const float4*)(oe0 + r1))[tid];
  {
    const float4 d = ((const float4*)(oe1 + r1))[tid];
    c.x += d.x; c.y += d.y; c.z += d.z; c.w += d.w;
  }
  float s0 = a.x * a.x + a.y * a.y + a.z * a.z + a.w * a.w;
  float s1 = c.x * c.x + c.y * c.y + c.z * c.z + c.w * c.w;
#pragma unroll
  for (int o = 32; o > 0; o >>= 1) {
    s0 += __shfl_xor(s0, o);
    s1 += __shfl_xor(s1, o);
  }
  __shared__ float red[8];
  if ((tid & 63) == 0) { red[tid >> 6] = s0; red[4 + (tid >> 6)] = s1; }
  __syncthreads();
  s0 = red[0] + red[1] + red[2] + red[3];
  s1 = red[4] + red[5] + red[6] + red[7];
  const float n0 = rsqrtf(s0 * (1.f / DMODEL) + RMS_EPS) * g.x;
  const float n1 = rsqrtf(s1 * (1.f / DMODEL) + RMS_EPS) * g.y;

  const float4 w0 = ((const float4*)(enw + (size_t)e0 * DMODEL))[tid];
  const float4 w1 = ((const float4*)(enw + (size_t)e1 * DMODEL))[tid];
  float4 v;
  v.x = a.x * n0 * w0.x + c.x * n1 * w1.x;
  v.y = a.y * n0 * w0.y + c.y * n1 * w1.y;
  v.z = a.z * n0 * w0.z + c.z * n1 * w1.z;
  v.w = a.w * n0 * w0.w + c.w * n1 * w1.w;

  float sv = v.x * v.x + v.y * v.y + v.z * v.z + v.w * v.w;
#pragma unroll
  for (int o = 32; o > 0; o >>= 1) sv += __shfl_xor(sv, o);
  __syncthreads();                      // red reuse
  if ((tid & 63) == 0) red[tid >> 6] = sv;
  __syncthreads();
  sv = red[0] + red[1] + red[2] + red[3];
  const float so = rsqrtf(sv * (1.f / DMODEL) + RMS_EPS);

  const float4 wo = ((const float4*)outnw)[tid];
  ushort4 o4;
  o4.x = f2bf(v.x * so * wo.x);
  o4.y = f2bf(v.y * so * wo.y);
  o4.z = f2bf(v.z * so * wo.z);
  o4.w = f2bf(v.w * so * wo.w);
  ((ushort4*)(yb + (long)row * DMODEL))[tid] = o4;
}

extern "C" void kernel_launch(void* const* d_in, const int* in_sizes, int n_in,
                              void* d_out, int out_size, void* d_ws, size_t ws_size,
                              hipStream_t stream) {
  (void)in_sizes; (void)n_in; (void)out_size; (void)ws_size;
  const float* s_in  = (const float*)d_in[0];
  const float* W_in  = (const float*)d_in[1];
  const float* innw  = (const float*)d_in[2];
  const float* Wr    = (const float*)d_in[3];
  const float* ebias = (const float*)d_in[4];
  const float* Wg    = (const float*)d_in[5];
  const float* Wu    = (const float*)d_in[6];
  const float* Wd    = (const float*)d_in[7];
  const float* enw   = (const float*)d_in[8];
  const float* outnw = (const float*)d_in[9];
  const float* W_out = (const float*)d_in[10];
  float* out = (float*)d_out;

  // ---- workspace layout (~527 MB) ----
  char* base = (char*)d_ws;
  size_t off_b = 0;
  auto alloc = [&](size_t bytes) -> char* {
    char* p = base + off_b;
    off_b += (bytes + 255) & ~(size_t)255;
    return p;
  };
  unsigned short* xb    = (unsigned short*)alloc((size_t)NT * DMODEL * 2);
  unsigned short* Winb  = (unsigned short*)alloc((size_t)DMODEL * DMODEL * 2);
  unsigned short* Wgb   = (unsigned short*)alloc((size_t)NEXP * DFF * DMODEL * 2);
  unsigned short* Wub   = (unsigned short*)alloc((size_t)NEXP * DFF * DMODEL * 2);
  unsigned short* Wdb   = (unsigned short*)alloc((size_t)NEXP * DMODEL * DFF * 2);
  unsigned short* Woutb = (unsigned short*)alloc((size_t)DMODEL * DMODEL * 2);
  float*          hpre  = (float*)alloc((size_t)NT * DMODEL * 4);
  unsigned short* hb    = (unsigned short*)alloc((size_t)NT * DMODEL * 2);
  float*          invr  = (float*)alloc((size_t)NT * 4);
  float*          Wr2   = (float*)alloc((size_t)NEXP * DMODEL * 4);
  int*            cnt   = (int*)alloc((size_t)NEXP * 4);
  int*            offs  = (int*)alloc((size_t)(NEXP + 1) * 4);
  int*            tok   = (int*)alloc((size_t)NEXP * NT * 4);
  int*            te    = (int*)alloc((size_t)NT * 4);
  int2*           ts    = (int2*)alloc((size_t)NT * 8);
  float2*         tg    = (float2*)alloc((size_t)NT * 8);
  unsigned short* Ac    = (unsigned short*)alloc((size_t)MAXROWS * DMODEL * 2);
  unsigned short* Hc    = (unsigned short*)alloc((size_t)MAXROWS * DFF * 2);
  float*          oec   = (float*)alloc((size_t)MAXROWS * DMODEL * 4);
  // aliases: yb over xb (dead after in-projection); oec2 (split-K partial 1,
  // 75.5 MB) over Wgb+Wub (dead after the fused gate/up GEMM).
  unsigned short* yb    = xb;
  float*          oec2  = (float*)Wgb;

  // ---- 1. casts + zero the slot counters ----
  hipMemsetAsync(cnt, 0, NEXP * 4, stream);
  cast_bf16_kernel<<<2048, 256, 0, stream>>>(s_in, xb, (long)NT * DMODEL);
  cast_bf16_kernel<<<2048, 256, 0, stream>>>(W_in, Winb, (long)DMODEL * DMODEL);
  cast_bf16_kernel<<<2048, 256, 0, stream>>>(Wg, Wgb, (long)NEXP * DFF * DMODEL);
  cast_bf16_kernel<<<2048, 256, 0, stream>>>(Wu, Wub, (long)NEXP * DFF * DMODEL);
  cast_bf16_kernel<<<2048, 256, 0, stream>>>(Wd, Wdb, (long)NEXP * DMODEL * DFF);
  cast_bf16_kernel<<<2048, 256, 0, stream>>>(W_out, Woutb, (long)DMODEL * DMODEL);

  // ---- 2. hpre = x @ W_in^T ; hb = rmsnorm(hpre)*innw (+invrms) ----
  gemm8ph<0, 0><<<dim3(NT / 256, DMODEL / 256), 512, 0, stream>>>(
      xb, Winb, nullptr, hpre, nullptr, nullptr, DMODEL, DMODEL / 64, 0);
  rmsnorm_kernel<<<NT, 256, 0, stream>>>(hpre, innw, hb, invr);

  // ---- 3. router + compaction ----
  router_prep_kernel<<<DMODEL / 128, 256, 0, stream>>>(Wr, innw, W_in, Wr2);
  router_kernel<<<NT, 64, 0, stream>>>(s_in, Wr2, ebias, invr, cnt, tok, te, ts, tg);
  pad_kernel<<<1, 256, 0, stream>>>(cnt, tok, offs);

  // ---- 4. gather compact A ----
  gather_kernel<<<MAXROWS, 256, 0, stream>>>(hb, tok, offs, Ac);

  // ---- 5. FUSED gate+up GEMM: Hc = silu(Ac@Wg^T) * (Ac@Wu^T), one pass ----
  gemm8ph<1, 1><<<dim3(MAXROWS / 256, DFF / 128), 512, 0, stream>>>(
      Ac, Wgb, Wub, Hc, nullptr, offs, DMODEL, DMODEL / 64, (size_t)DFF * DMODEL);

  // ---- 6. down projection, split-K=2 (z: k in [0,2048) / [2048,4096)) ----
  gemm8ph<0, 1><<<dim3(MAXROWS / 256, DMODEL / 256, 2), 512, 0, stream>>>(
      Hc, Wdb, nullptr, oec, oec2, offs, DFF, 32, (size_t)DMODEL * DFF);

  // ---- 7. per-token combine (expert rmsnorm + gates + final rmsnorm) ----
  combine_kernel<<<NT, 256, 0, stream>>>(
      oec, oec2, enw, outnw, offs, te, ts, tg, yb);

  // ---- 8. output projection ----
  gemm8ph<0, 0><<<dim3(NT / 256, DMODEL / 256), 512, 0, stream>>>(
      yb, Woutb, nullptr, out, nullptr, nullptr, DMODEL, DMODEL / 64, 0);
}

// Round 4
// 1365.545 us; speedup vs baseline: 1.3172x; 1.0071x over previous
//
#include <hip/hip_runtime.h>

// ---------------------------------------------------------------------------
// MoEPredictor on MI355X (gfx950) — Round 7: overhead elimination.
//   * one fused cast kernel (6 dispatches -> 1)
//   * gather folded into the fused GEMM staging (per-lane global src of
//     global_load_lds reads hb[tok[row]] directly; Ac buffer removed)
//   * in-projection split-K=2 -> 256-block grid (exactly 1 CU round),
//     partials summed in rmsnorm2
//   * dispatch count 22 -> 12
// GEMM core unchanged from R5/R6 (8-phase counted-vmcnt, T1/T2/T5; at the
// m248-documented 34%-of-peak level for grouped 256^2 K=1024).
// ---------------------------------------------------------------------------

#define NT      8192
#define DMODEL  1024
#define DFF     4096
#define NEXP    8
#define MAXROWS (NT * 2 + NEXP * 256)  // 18432 padded compact rows max
#define RMS_EPS 1.1920928955078125e-07f  // jnp.finfo(float32).eps

typedef __attribute__((ext_vector_type(8))) short bf16x8;   // MFMA A/B frag
typedef __attribute__((ext_vector_type(4))) float f32x4;    // MFMA C/D frag

__device__ __forceinline__ float bf2f(unsigned short u) {
  union { unsigned int i; float f; } c; c.i = ((unsigned int)u) << 16; return c.f;
}
__device__ __forceinline__ unsigned short f2bf(float f) {
  union { float f; unsigned int i; } c; c.f = f;
  unsigned int x = c.i;
  return (unsigned short)((x + 0x7FFFu + ((x >> 16) & 1u)) >> 16);  // RNE
}

#define BARX() __builtin_amdgcn_s_barrier()
#define LGKM0() do { asm volatile("s_waitcnt lgkmcnt(0)" ::: "memory"); \
                     __builtin_amdgcn_sched_barrier(0); } while (0)
#define VMC(n)  do { asm volatile("s_waitcnt vmcnt(" #n ")" ::: "memory"); \
                     __builtin_amdgcn_sched_barrier(0); } while (0)

// ---- one-shot cast of all f32 inputs to bf16 (segment table is constexpr) --
// seg elems: s 8388608 | W_in 1048576 | Wg 33554432 | Wu 33554432 |
//            Wd 33554432 | W_out 1048576 ; total 111149056
__global__ __launch_bounds__(256) void cast_all_kernel(
    const float* __restrict__ s0, const float* __restrict__ s1,
    const float* __restrict__ s2, const float* __restrict__ s3,
    const float* __restrict__ s4, const float* __restrict__ s5,
    unsigned short* __restrict__ d0, unsigned short* __restrict__ d1,
    unsigned short* __restrict__ d2, unsigned short* __restrict__ d3,
    unsigned short* __restrict__ d4, unsigned short* __restrict__ d5) {
  long i = ((long)blockIdx.x * 256 + threadIdx.x) * 4;
  const long stride = (long)gridDim.x * 1024;
  for (; i < 111149056L; i += stride) {
    const float* s; unsigned short* d; long o;
    if (i < 8388608L)        { s = s0; d = d0; o = 0L; }
    else if (i < 9437184L)   { s = s1; d = d1; o = 8388608L; }
    else if (i < 42991616L)  { s = s2; d = d2; o = 9437184L; }
    else if (i < 76546048L)  { s = s3; d = d3; o = 42991616L; }
    else if (i < 110100480L) { s = s4; d = d4; o = 76546048L; }
    else                     { s = s5; d = d5; o = 110100480L; }
    const long j = i - o;
    float4 v = *(const float4*)(s + j);
    ushort4 u;
    u.x = f2bf(v.x); u.y = f2bf(v.y); u.z = f2bf(v.z); u.w = f2bf(v.w);
    *(ushort4*)(d + j) = u;
  }
}

// ---- async global->LDS 16B (wave-uniform base + lane*16 layout) ----
__device__ __forceinline__ void async_cp16(const void* g, void* l) {
  __builtin_amdgcn_global_load_lds((const __attribute__((address_space(1))) void*)g,
                                   (__attribute__((address_space(3))) void*)l, 16, 0, 0);
}

// ---------------------------------------------------------------------------
// 8-phase GEMM, 256 rows x 256 B-rows x K, counted vmcnt (R5 schedule).
// FUSED=1: Wg/Wu interleaved B, bf16 silu-combined out (ld = DFF, 128 cols).
// FUSED=0: plain B^T from W0, f32 out (ld = DMODEL), split-K via gridDim.z.
// GROUPED=0: dense A (e = 0, no early exit).
// GATHER=1 (requires GROUPED): A-row source indices come from tokp
//   (per-lane global src of global_load_lds — LDS dest stays linear).
// ---------------------------------------------------------------------------
template <int FUSED, int GROUPED, int GATHER>
__global__ __launch_bounds__(512, 2) void gemm8ph(
    const unsigned short* __restrict__ A,
    const unsigned short* __restrict__ W0,   // Wg (fused) / Wd / W_in / W_out
    const unsigned short* __restrict__ W1,   // Wu (fused) / unused
    void* __restrict__ Cv, void* __restrict__ Cv2,
    const int* __restrict__ offs, const int* __restrict__ tokp,
    int K, int KT, size_t wstride) {
  // ---- T1: bijective XCD-aware block swizzle (m204) on the x/y plane ----
  const int gx = gridDim.x;
  const int nwg = gx * gridDim.y;
  int bid = blockIdx.y * gx + blockIdx.x;
  {
    const int q = nwg >> 3, r = nwg & 7;
    const int x = bid & 7, l = bid >> 3;
    bid = (x < r ? x * (q + 1) : r * (q + 1) + (x - r) * q) + l;
  }
  const int bx = bid % gx, by = bid / gx;

  const int row0 = bx * 256;
  int e = 0, seg0 = 0;
  if constexpr (GROUPED) {
    if (row0 >= offs[NEXP]) return;   // uniform early-exit before any barrier
#pragma unroll
    for (int i = 1; i < NEXP; ++i) e += (row0 >= offs[i]) ? 1 : 0;
    seg0 = offs[e];
  }

  // LDS: 2 dbuf x {A,B} x 2 K-halves x [256 rows][32 k] bf16 = 128 KB
  // short-offsets: buf<<15 | isB<<14 | ks<<13 | row*32 | slot*8
  __shared__ __align__(16) unsigned short lds[65536];

  const int t = threadIdx.x;
  const int lane = t & 63;
  const int wave = t >> 6;
  const int wm = wave >> 2, wn = wave & 3;   // 2 x 4 waves
  const int lm = lane & 15, kq = lane >> 4;
  const int k0 = blockIdx.z * (KT << 6);     // split-K start (elements)

  // ---- staging setup: thread t, load q covers linear slot L = q*512+t ----
  // LDS slot (row = L>>2, slot = t&3) holds global k-quad kq' = slot ^ f(row),
  // f(row) = (row>>1)&3  (inverse-swizzled source, linear dest — rule 21).
  const unsigned short* aP[2];
  const unsigned short* bP[2];
  int dl[2];
#pragma unroll
  for (int q = 0; q < 2; ++q) {
    const int L = q * 512 + t;
    const int row = L >> 2;
    const int kp = (t & 3) ^ ((row >> 1) & 3);
    dl[q] = L * 8;                                    // shorts
    size_t ar;
    if constexpr (GATHER) ar = (size_t)tokp[e * NT + (row0 + row - seg0)];
    else                  ar = (size_t)(row0 + row);
    aP[q] = A + ar * K + kp * 8 + k0;
    if (FUSED) {
      const int f = by * 128 + ((row >> 6) << 5) + (row & 31);
      const unsigned short* wb = (row & 32) ? W1 : W0;
      bP[q] = wb + (size_t)e * wstride + (size_t)f * K + kp * 8 + k0;
    } else {
      bP[q] = W0 + (size_t)e * wstride + (size_t)(by * 256 + row) * K + kp * 8 + k0;
    }
  }

  // ---- ds_read offsets (shorts), swizzled: slot = kq ^ ((row>>1)&3) ----
  int afo[8], bfo[4];
#pragma unroll
  for (int mi = 0; mi < 8; ++mi) {
    const int r = wm * 128 + mi * 16 + lm;
    afo[mi] = r * 32 + ((kq ^ ((r >> 1) & 3)) << 3);
  }
#pragma unroll
  for (int ni = 0; ni < 4; ++ni) {
    const int r = wn * 64 + ni * 16 + lm;
    bfo[ni] = 16384 + r * 32 + ((kq ^ ((r >> 1) & 3)) << 3);
  }

  f32x4 acc[8][4];
#pragma unroll
  for (int i = 0; i < 8; ++i)
#pragma unroll
    for (int j = 0; j < 4; ++j) acc[i][j] = (f32x4){0.f, 0.f, 0.f, 0.f};

  auto STG = [&](int tau, int ks, int isB) {
    const int roff = ((tau & 1) << 15) + (isB << 14) + (ks << 13);
    const int koff = (tau << 6) + (ks << 5);
#pragma unroll
    for (int q = 0; q < 2; ++q)
      async_cp16((isB ? bP[q] : aP[q]) + koff, lds + roff + dl[q]);
  };

  // ---- prologue: tile0 {A0,B0,A1,B1} + tile1 {A0,B0,A1}; 3 halves in flight
  STG(0, 0, 0); STG(0, 0, 1); STG(0, 1, 0); STG(0, 1, 1);
  STG(1, 0, 0); STG(1, 0, 1); STG(1, 1, 0);
  VMC(6);
  BARX();

  for (int tau = 0; tau < KT; ++tau) {
    const int tb = (tau & 1) << 15;
    const bool s1 = (tau + 1 < KT), s2 = (tau + 2 < KT);
    bf16x8 af[8], bq0, bq1;

    // ---- q0: ks0, N-low ----
#pragma unroll
    for (int mi = 0; mi < 8; ++mi) af[mi] = *(const bf16x8*)(lds + tb + afo[mi]);
    bq0 = *(const bf16x8*)(lds + tb + bfo[0]);
    bq1 = *(const bf16x8*)(lds + tb + bfo[1]);
    if (s1) STG(tau + 1, 1, 1);                 // B1(tau+1) -> other buf
    BARX(); LGKM0();
    __builtin_amdgcn_s_setprio(1);
#pragma unroll
    for (int mi = 0; mi < 8; ++mi) {
      acc[mi][0] = __builtin_amdgcn_mfma_f32_16x16x32_bf16(af[mi], bq0, acc[mi][0], 0, 0, 0);
      acc[mi][1] = __builtin_amdgcn_mfma_f32_16x16x32_bf16(af[mi], bq1, acc[mi][1], 0, 0, 0);
    }
    __builtin_amdgcn_s_setprio(0);
    BARX();

    // ---- q1: ks0, N-high ----
    bq0 = *(const bf16x8*)(lds + tb + bfo[2]);
    bq1 = *(const bf16x8*)(lds + tb + bfo[3]);
    if (s2) STG(tau + 2, 0, 0);                 // A0(tau+2), A0 dead after q0
    BARX(); LGKM0();
    __builtin_amdgcn_s_setprio(1);
#pragma unroll
    for (int mi = 0; mi < 8; ++mi) {
      acc[mi][2] = __builtin_amdgcn_mfma_f32_16x16x32_bf16(af[mi], bq0, acc[mi][2], 0, 0, 0);
      acc[mi][3] = __builtin_amdgcn_mfma_f32_16x16x32_bf16(af[mi], bq1, acc[mi][3], 0, 0, 0);
    }
    __builtin_amdgcn_s_setprio(0);
    BARX();

    // ---- q2: ks1, N-low ----
#pragma unroll
    for (int mi = 0; mi < 8; ++mi) af[mi] = *(const bf16x8*)(lds + tb + 8192 + afo[mi]);
    bq0 = *(const bf16x8*)(lds + tb + 8192 + bfo[0]);
    bq1 = *(const bf16x8*)(lds + tb + 8192 + bfo[1]);
    if (s2) STG(tau + 2, 0, 1);                 // B0(tau+2), B0 dead after q1
    BARX(); LGKM0();
    __builtin_amdgcn_s_setprio(1);
#pragma unroll
    for (int mi = 0; mi < 8; ++mi) {
      acc[mi][0] = __builtin_amdgcn_mfma_f32_16x16x32_bf16(af[mi], bq0, acc[mi][0], 0, 0, 0);
      acc[mi][1] = __builtin_amdgcn_mfma_f32_16x16x32_bf16(af[mi], bq1, acc[mi][1], 0, 0, 0);
    }
    __builtin_amdgcn_s_setprio(0);
    BARX();

    // ---- q3: ks1, N-high ----
    bq0 = *(const bf16x8*)(lds + tb + 8192 + bfo[2]);
    bq1 = *(const bf16x8*)(lds + tb + 8192 + bfo[3]);
    if (s2) STG(tau + 2, 1, 0);                 // A1(tau+2), A1 dead after q2
    BARX(); LGKM0();
    __builtin_amdgcn_s_setprio(1);
#pragma unroll
    for (int mi = 0; mi < 8; ++mi) {
      acc[mi][2] = __builtin_amdgcn_mfma_f32_16x16x32_bf16(af[mi], bq0, acc[mi][2], 0, 0, 0);
      acc[mi][3] = __builtin_amdgcn_mfma_f32_16x16x32_bf16(af[mi], bq1, acc[mi][3], 0, 0, 0);
    }
    __builtin_amdgcn_s_setprio(0);
    // counted vmcnt: waits tile tau+1 complete, leaves tau+2's 3 halves flying
    if (tau + 3 <= KT) { VMC(6); }
    else if (tau + 2 == KT) { VMC(0); }
    BARX();
  }

  // ---- epilogue — C/D: row = +kq*4+rr, col = +lm (verified mapping) ----
  const long rbase = (long)row0 + wm * 128 + kq * 4;
  if (FUSED) {
    unsigned short* Hc = (unsigned short*)Cv;
    const int cb = by * 128 + wn * 32 + lm;
#pragma unroll
    for (int mi = 0; mi < 8; ++mi)
#pragma unroll
      for (int ni = 0; ni < 2; ++ni)
#pragma unroll
        for (int rr = 0; rr < 4; ++rr) {
          const float g = acc[mi][ni][rr];
          const float u = acc[mi][ni + 2][rr];
          const float h = g / (1.f + expf(-g)) * u;
          Hc[(rbase + mi * 16 + rr) * (long)DFF + cb + ni * 16] = f2bf(h);
        }
  } else {
    float* Cp = blockIdx.z ? (float*)Cv2 : (float*)Cv;
    const int cb = by * 256 + wn * 64 + lm;
#pragma unroll
    for (int mi = 0; mi < 8; ++mi)
#pragma unroll
      for (int ni = 0; ni < 4; ++ni)
#pragma unroll
        for (int rr = 0; rr < 4; ++rr)
          Cp[(rbase + mi * 16 + rr) * (long)DMODEL + cb + ni * 16] = acc[mi][ni][rr];
  }
}

// ---- rmsnorm over sum of two split-K partials: bf16 out + invrms ----
__global__ __launch_bounds__(256) void rmsnorm2_kernel(
    const float* __restrict__ in0, const float* __restrict__ in1,
    const float* __restrict__ w,
    unsigned short* __restrict__ out, float* __restrict__ invrms) {
  const int row = blockIdx.x;
  const int tid = threadIdx.x;
  float4 xv = ((const float4*)(in0 + (long)row * DMODEL))[tid];
  const float4 yv = ((const float4*)(in1 + (long)row * DMODEL))[tid];
  xv.x += yv.x; xv.y += yv.y; xv.z += yv.z; xv.w += yv.w;
  float ss = xv.x * xv.x + xv.y * xv.y + xv.z * xv.z + xv.w * xv.w;
#pragma unroll
  for (int o = 32; o > 0; o >>= 1) ss += __shfl_xor(ss, o);
  __shared__ float red[4];
  if ((tid & 63) == 0) red[tid >> 6] = ss;
  __syncthreads();
  const float tot = red[0] + red[1] + red[2] + red[3];
  const float s = rsqrtf(tot * (1.f / DMODEL) + RMS_EPS);
  if (tid == 0) invrms[row] = s;
  const float4 wv = ((const float4*)w)[tid];
  ushort4 o4;
  o4.x = f2bf(xv.x * s * wv.x);
  o4.y = f2bf(xv.y * s * wv.y);
  o4.z = f2bf(xv.z * s * wv.z);
  o4.w = f2bf(xv.w * s * wv.w);
  ((ushort4*)(out + (long)row * DMODEL))[tid] = o4;
}

// ---- fold router weight through W_in: Wr2[e,k] = sum_j Wr[e,j]*nw[j]*W_in[j,k]
__global__ __launch_bounds__(256) void router_prep_kernel(
    const float* __restrict__ Wr, const float* __restrict__ nw,
    const float* __restrict__ W_in, float* __restrict__ Wr2) {
  __shared__ float wr[NEXP * DMODEL];  // 32 KB
  const int tid = threadIdx.x;
  for (int i = tid; i < NEXP * DMODEL; i += 256) wr[i] = Wr[i] * nw[i & (DMODEL - 1)];
  __syncthreads();
  const int kl = tid & 127;
  const int eb = (tid >> 7) * 4;
  const int kg = blockIdx.x * 128 + kl;
  float a0 = 0.f, a1 = 0.f, a2 = 0.f, a3 = 0.f;
  for (int j = 0; j < DMODEL; ++j) {
    const float wij = W_in[(long)j * DMODEL + kg];
    a0 += wr[(eb + 0) * DMODEL + j] * wij;
    a1 += wr[(eb + 1) * DMODEL + j] * wij;
    a2 += wr[(eb + 2) * DMODEL + j] * wij;
    a3 += wr[(eb + 3) * DMODEL + j] * wij;
  }
  Wr2[(eb + 0) * DMODEL + kg] = a0;
  Wr2[(eb + 1) * DMODEL + kg] = a1;
  Wr2[(eb + 2) * DMODEL + kg] = a2;
  Wr2[(eb + 3) * DMODEL + kg] = a3;
}

// ---- router: fp32 logits, top-2, softmax; compact lists + per-token maps ----
__global__ __launch_bounds__(64) void router_kernel(
    const float* __restrict__ x, const float* __restrict__ Wr2,
    const float* __restrict__ bias, const float* __restrict__ invrms,
    int* __restrict__ cnt, int* __restrict__ tok,
    int* __restrict__ te, int2* __restrict__ ts, float2* __restrict__ tg) {
  const int row = blockIdx.x;
  const int lane = threadIdx.x;
  const float* xr = x + (long)row * DMODEL;
  float p[NEXP] = {0.f, 0.f, 0.f, 0.f, 0.f, 0.f, 0.f, 0.f};
  for (int k = lane; k < DMODEL; k += 64) {
    const float xv = xr[k];
#pragma unroll
    for (int e = 0; e < NEXP; ++e) p[e] += xv * Wr2[e * DMODEL + k];
  }
#pragma unroll
  for (int o = 32; o > 0; o >>= 1)
#pragma unroll
    for (int e = 0; e < NEXP; ++e) p[e] += __shfl_xor(p[e], o);
  if (lane == 0) {
    const float s = invrms[row];
    float logit[NEXP];
    float b0 = -1e30f, b1 = -1e30f;
    int i0 = 0, i1 = 0;
#pragma unroll
    for (int e = 0; e < NEXP; ++e) {
      logit[e] = p[e] * s;
      const float be = logit[e] + bias[e];
      if (be > b0)      { b1 = b0; i1 = i0; b0 = be; i0 = e; }
      else if (be > b1) { b1 = be; i1 = e; }
    }
    const float l0 = logit[i0], l1 = logit[i1];
    const float m = fmaxf(l0, l1);
    const float e0 = expf(l0 - m), e1 = expf(l1 - m);
    const float inv = 1.f / (e0 + e1);
    const int s0 = atomicAdd(&cnt[i0], 1);
    tok[i0 * NT + s0] = row;
    const int s1 = atomicAdd(&cnt[i1], 1);
    tok[i1 * NT + s1] = row;
    te[row] = i0 | (i1 << 8);
    ts[row] = make_int2(s0, s1);
    tg[row] = make_float2(e0 * inv, e1 * inv);
  }
}

// ---- pad counts to 256-multiples, prefix-sum offsets, fill pad slots ----
__global__ __launch_bounds__(256) void pad_kernel(
    const int* __restrict__ cnt, int* __restrict__ tok, int* __restrict__ off) {
  __shared__ int sc[NEXP], sp[NEXP];
  const int tid = threadIdx.x;
  if (tid == 0) {
    int o = 0;
    for (int e = 0; e < NEXP; ++e) {
      const int c = cnt[e];
      const int p = (c + 255) & ~255;
      sc[e] = c; sp[e] = p;
      off[e] = o;
      o += p;
    }
    off[NEXP] = o;
  }
  __syncthreads();
  for (int e = 0; e < NEXP; ++e) {
    const int c = sc[e], p = sp[e];
    for (int s = c + tid; s < p; s += 256) tok[e * NT + s] = 0;
  }
}

// ---- per-token combine: expert rmsnorm + gates + final rmsnorm, one pass ----
// yb[row] = bf16( rmsnorm( sum_e g_e * rmsnorm(oec[r_e]+oec2[r_e]) * enw[e] )
//                 * outnw )
__global__ __launch_bounds__(256) void combine_kernel(
    const float* __restrict__ oe0, const float* __restrict__ oe1,
    const float* __restrict__ enw, const float* __restrict__ outnw,
    const int* __restrict__ offs, const int* __restrict__ te,
    const int2* __restrict__ ts, const float2* __restrict__ tg,
    unsigned short* __restrict__ yb) {
  const int row = blockIdx.x;
  const int tid = threadIdx.x;
  const int pe = te[row];
  const int e0 = pe & 0xff, e1 = (pe >> 8) & 0xff;
  const int2 sl = ts[row];
  const float2 g = tg[row];
  const long r0 = (long)(offs[e0] + sl.x) * DMODEL;
  const long r1 = (long)(offs[e1] + sl.y) * DMODEL;

  float4 a = ((const float4*)(oe0 + r0))[tid];
  {
    const float4 b = ((const float4*)(oe1 + r0))[tid];
    a.x += b.x; a.y += b.y; a.z += b.z; a.w += b.w;
  }
  float4 c = ((const float4*)(oe0 + r1))[tid];
  {
    const float4 d = ((const float4*)(oe1 + r1))[tid];
    c.x += d.x; c.y += d.y; c.z += d.z; c.w += d.w;
  }
  float s0 = a.x * a.x + a.y * a.y + a.z * a.z + a.w * a.w;
  float s1 = c.x * c.x + c.y * c.y + c.z * c.z + c.w * c.w;
#pragma unroll
  for (int o = 32; o > 0; o >>= 1) {
    s0 += __shfl_xor(s0, o);
    s1 += __shfl_xor(s1, o);
  }
  __shared__ float red[8];
  if ((tid & 63) == 0) { red[tid >> 6] = s0; red[4 + (tid >> 6)] = s1; }
  __syncthreads();
  s0 = red[0] + red[1] + red[2] + red[3];
  s1 = red[4] + red[5] + red[6] + red[7];
  const float n0 = rsqrtf(s0 * (1.f / DMODEL) + RMS_EPS) * g.x;
  const float n1 = rsqrtf(s1 * (1.f / DMODEL) + RMS_EPS) * g.y;

  const float4 w0 = ((const float4*)(enw + (size_t)e0 * DMODEL))[tid];
  const float4 w1 = ((const float4*)(enw + (size_t)e1 * DMODEL))[tid];
  float4 v;
  v.x = a.x * n0 * w0.x + c.x * n1 * w1.x;
  v.y = a.y * n0 * w0.y + c.y * n1 * w1.y;
  v.z = a.z * n0 * w0.z + c.z * n1 * w1.z;
  v.w = a.w * n0 * w0.w + c.w * n1 * w1.w;

  float sv = v.x * v.x + v.y * v.y + v.z * v.z + v.w * v.w;
#pragma unroll
  for (int o = 32; o > 0; o >>= 1) sv += __shfl_xor(sv, o);
  __syncthreads();                      // red reuse
  if ((tid & 63) == 0) red[tid >> 6] = sv;
  __syncthreads();
  sv = red[0] + red[1] + red[2] + red[3];
  const float so = rsqrtf(sv * (1.f / DMODEL) + RMS_EPS);

  const float4 wo = ((const float4*)outnw)[tid];
  ushort4 o4;
  o4.x = f2bf(v.x * so * wo.x);
  o4.y = f2bf(v.y * so * wo.y);
  o4.z = f2bf(v.z * so * wo.z);
  o4.w = f2bf(v.w * so * wo.w);
  ((ushort4*)(yb + (long)row * DMODEL))[tid] = o4;
}

extern "C" void kernel_launch(void* const* d_in, const int* in_sizes, int n_in,
                              void* d_out, int out_size, void* d_ws, size_t ws_size,
                              hipStream_t stream) {
  (void)in_sizes; (void)n_in; (void)out_size; (void)ws_size;
  const float* s_in  = (const float*)d_in[0];
  const float* W_in  = (const float*)d_in[1];
  const float* innw  = (const float*)d_in[2];
  const float* Wr    = (const float*)d_in[3];
  const float* ebias = (const float*)d_in[4];
  const float* Wg    = (const float*)d_in[5];
  const float* Wu    = (const float*)d_in[6];
  const float* Wd    = (const float*)d_in[7];
  const float* enw   = (const float*)d_in[8];
  const float* outnw = (const float*)d_in[9];
  const float* W_out = (const float*)d_in[10];
  float* out = (float*)d_out;

  // ---- workspace layout (~533 MB) ----
  char* base = (char*)d_ws;
  size_t off_b = 0;
  auto alloc = [&](size_t bytes) -> char* {
    char* p = base + off_b;
    off_b += (bytes + 255) & ~(size_t)255;
    return p;
  };
  unsigned short* xb    = (unsigned short*)alloc((size_t)NT * DMODEL * 2);
  unsigned short* Winb  = (unsigned short*)alloc((size_t)DMODEL * DMODEL * 2);
  unsigned short* Wgb   = (unsigned short*)alloc((size_t)NEXP * DFF * DMODEL * 2);
  unsigned short* Wub   = (unsigned short*)alloc((size_t)NEXP * DFF * DMODEL * 2);
  unsigned short* Wdb   = (unsigned short*)alloc((size_t)NEXP * DMODEL * DFF * 2);
  unsigned short* Woutb = (unsigned short*)alloc((size_t)DMODEL * DMODEL * 2);
  float*          hpre0 = (float*)alloc((size_t)NT * DMODEL * 4);
  float*          hpre1 = (float*)alloc((size_t)NT * DMODEL * 4);
  unsigned short* hb    = (unsigned short*)alloc((size_t)NT * DMODEL * 2);
  float*          invr  = (float*)alloc((size_t)NT * 4);
  float*          Wr2   = (float*)alloc((size_t)NEXP * DMODEL * 4);
  int*            cnt   = (int*)alloc((size_t)NEXP * 4);
  int*            offs  = (int*)alloc((size_t)(NEXP + 1) * 4);
  int*            tok   = (int*)alloc((size_t)NEXP * NT * 4);
  int*            te    = (int*)alloc((size_t)NT * 4);
  int2*           ts    = (int2*)alloc((size_t)NT * 8);
  float2*         tg    = (float2*)alloc((size_t)NT * 8);
  unsigned short* Hc    = (unsigned short*)alloc((size_t)MAXROWS * DFF * 2);
  float*          oec   = (float*)alloc((size_t)MAXROWS * DMODEL * 4);
  // aliases: yb over xb (dead after in-projection); oec2 (split-K partial 1,
  // 75.5 MB) over Wgb(+start of Wub) — both dead after the fused GEMM.
  unsigned short* yb    = xb;
  float*          oec2  = (float*)Wgb;

  // ---- 1. zero slot counters + one-shot cast of all inputs ----
  hipMemsetAsync(cnt, 0, NEXP * 4, stream);
  cast_all_kernel<<<2048, 256, 0, stream>>>(
      s_in, W_in, Wg, Wu, Wd, W_out, xb, Winb, Wgb, Wub, Wdb, Woutb);

  // ---- 2. in-projection, split-K=2 (256 blocks = 1 full CU round) ----
  gemm8ph<0, 0, 0><<<dim3(NT / 256, DMODEL / 256, 2), 512, 0, stream>>>(
      xb, Winb, nullptr, hpre0, hpre1, nullptr, nullptr, DMODEL, 8, 0);
  rmsnorm2_kernel<<<NT, 256, 0, stream>>>(hpre0, hpre1, innw, hb, invr);

  // ---- 3. router + compaction ----
  router_prep_kernel<<<DMODEL / 128, 256, 0, stream>>>(Wr, innw, W_in, Wr2);
  router_kernel<<<NT, 64, 0, stream>>>(s_in, Wr2, ebias, invr, cnt, tok, te, ts, tg);
  pad_kernel<<<1, 256, 0, stream>>>(cnt, tok, offs);

  // ---- 4. FUSED gate+up GEMM with in-staging gather from hb ----
  gemm8ph<1, 1, 1><<<dim3(MAXROWS / 256, DFF / 128), 512, 0, stream>>>(
      hb, Wgb, Wub, Hc, nullptr, offs, tok, DMODEL, DMODEL / 64,
      (size_t)DFF * DMODEL);

  // ---- 5. down projection, split-K=2 (z: k in [0,2048) / [2048,4096)) ----
  gemm8ph<0, 1, 0><<<dim3(MAXROWS / 256, DMODEL / 256, 2), 512, 0, stream>>>(
      Hc, Wdb, nullptr, oec, oec2, offs, nullptr, DFF, 32, (size_t)DMODEL * DFF);

  // ---- 6. per-token combine (expert rmsnorm + gates + final rmsnorm) ----
  combine_kernel<<<NT, 256, 0, stream>>>(
      oec, oec2, enw, outnw, offs, te, ts, tg, yb);

  // ---- 7. output projection ----
  gemm8ph<0, 0, 0><<<dim3(NT / 256, DMODEL / 256), 512, 0, stream>>>(
      yb, Woutb, nullptr, out, nullptr, nullptr, nullptr, DMODEL, DMODEL / 64, 0);
}